// Round 12
// baseline (580.765 us; speedup 1.0000x reference)
//
#include <hip/hip_runtime.h>

#define DMODEL 2048
#define SEQ    2048
#define BATCH  4
#define HEADS  16
#define DHEAD  128

typedef __attribute__((ext_vector_type(8))) short short8;
typedef __attribute__((ext_vector_type(4))) float f32x4;
typedef __attribute__((ext_vector_type(16))) float f32x16;

__device__ __forceinline__ unsigned short f2bf(float f) {
  union { float f; unsigned u; } v; v.f = f;
  unsigned r = v.u + 0x7FFFu + ((v.u >> 16) & 1u);
  return (unsigned short)(r >> 16);
}

// ---------------- prep: fp32 -> bf16 (vectorized) ----------------
__global__ __launch_bounds__(256) void cvt_f32_bf16(const float* __restrict__ in,
                                                    unsigned short* __restrict__ out,
                                                    int n4) {
  int i = blockIdx.x * 256 + threadIdx.x;
  if (i >= n4) return;
  float4 v = ((const float4*)in)[i];
  ushort4 o;
  o.x = f2bf(v.x); o.y = f2bf(v.y); o.z = f2bf(v.z); o.w = f2bf(v.w);
  ((ushort4*)out)[i] = o;
}

// ---------------- prep: 4x W[k][n] fp32 -> WT[n][k] bf16, fused ----------------
__global__ __launch_bounds__(256) void transpose_cvt4(const float* __restrict__ w0,
                                                      const float* __restrict__ w1,
                                                      const float* __restrict__ w2,
                                                      const float* __restrict__ w3,
                                                      unsigned short* __restrict__ o0,
                                                      unsigned short* __restrict__ o1,
                                                      unsigned short* __restrict__ o2,
                                                      unsigned short* __restrict__ o3) {
  __shared__ float tile[32][33];
  const int z = blockIdx.z;
  const float* in = (z == 0) ? w0 : (z == 1) ? w1 : (z == 2) ? w2 : w3;
  unsigned short* out = (z == 0) ? o0 : (z == 1) ? o1 : (z == 2) ? o2 : o3;
  const int tx = threadIdx.x, ty = threadIdx.y;
  const int x = blockIdx.x * 32 + tx;
  const int y0 = blockIdx.y * 32;
#pragma unroll
  for (int j = 0; j < 32; j += 8)
    tile[ty + j][tx] = in[(size_t)(y0 + ty + j) * DMODEL + x];
  __syncthreads();
  const int xo = blockIdx.y * 32 + tx;
  const int yo0 = blockIdx.x * 32;
#pragma unroll
  for (int j = 0; j < 32; j += 8)
    out[(size_t)(yo0 + ty + j) * DMODEL + xo] = f2bf(tile[tx][ty + j]);
}

// ---------------- V transpose: Vb[8192][2048] -> VT[64 bh][128 d][2048 l] ----------------
__global__ __launch_bounds__(256) void transpose_v(const unsigned short* __restrict__ in,
                                                   unsigned short* __restrict__ out) {
  __shared__ unsigned short t[32][33];
  const int tx = threadIdx.x, ty = threadIdx.y;
  const int bid = blockIdx.x;
  const int lb = bid & 63;
  const int db = (bid >> 6) & 3;
  const int h  = (bid >> 8) & 15;
  const int b  = bid >> 12;
#pragma unroll
  for (int j = 0; j < 32; j += 8)
    t[ty + j][tx] = in[(size_t)(b * SEQ + lb * 32 + ty + j) * DMODEL + h * DHEAD + db * 32 + tx];
  __syncthreads();
  const size_t ob = ((size_t)(b * HEADS + h) * DHEAD + db * 32) * SEQ + lb * 32;
#pragma unroll
  for (int j = 0; j < 32; j += 8)
    out[ob + (size_t)(ty + j) * SEQ + tx] = t[tx][ty + j];
}

// ---------------- GEMM v5: 256x256, BK=32, dbuf (64 KB LDS -> 2 blocks/CU) ----------------
// R7 gemm3 body (proven correct, conflicts=0) with the launch-bounds bug fixed:
// __launch_bounds__(512, 2) keeps the 256-VGPR budget (acc[8][4]=128 VGPR, no spill).
// Skeleton: BAR; STAGE(4); vmcnt(4); BAR; compute. 2 blocks/CU provide cross-block overlap.
// Block mapping (R10-proven FETCH reduction): NTN=24 -> 2D XCD partition with 4x4
// micro-tiles; NTN=8 -> tn-major per XCD.
// LDS [buf][256 r][32 c]; 16B-chunk p of row r holds logical chunk p^((r>>1)&3).
template <typename OUT_T, int NTN>
__global__ __launch_bounds__(512, 2) void gemm3(const unsigned short* __restrict__ A,
                                                const unsigned short* __restrict__ Bt,
                                                const float* __restrict__ b0,
                                                const float* __restrict__ b1,
                                                const float* __restrict__ b2,
                                                OUT_T* __restrict__ C) {
  __shared__ unsigned short As[2][256 * 32];
  __shared__ unsigned short Bs[2][256 * 32];

  const int tid = threadIdx.x;
  const int l = tid & 63, w = tid >> 6;
  const int wr = w >> 2, wc = w & 3;

  const int bid = blockIdx.x;
  int tm, tn;
  if constexpr (NTN == 24) {
    const int xcd = bid & 7;
    const int idx = bid >> 3;        // 0..95
    const int r = xcd >> 1, c = xcd & 1;
    const int mt = idx >> 4;         // 0..5 micro-tile
    const int i = idx & 15;
    const int mrow = mt & 1, mcol = mt >> 1;   // 2 x 3
    tm = r * 8 + mrow * 4 + (i & 3);
    tn = c * 12 + mcol * 4 + (i >> 2);
  } else {
    const int q8 = (32 * NTN) >> 3;
    const int swz = (bid & 7) * q8 + (bid >> 3);
    tn = swz % NTN;
    tm = swz / NTN;
  }

  // staging: 4 loads/thread/K-tile (A slab0/slab1, B slab0/slab1; slab = 128 rows)
  const int srow = tid >> 2;                          // 0..127 (row within slab)
  const int schunk = (tid & 3) ^ ((tid >> 3) & 3);    // pre-swizzled source chunk
  const unsigned short* Ag0 = A + (size_t)(tm * 256 + srow) * DMODEL + schunk * 8;
  const unsigned short* Ag1 = Ag0 + (size_t)128 * DMODEL;
  const unsigned short* Bg0 = Bt + (size_t)(tn * 256 + srow) * DMODEL + schunk * 8;
  const unsigned short* Bg1 = Bg0 + (size_t)128 * DMODEL;

#define GLL(src, dst) __builtin_amdgcn_global_load_lds( \
    (const __attribute__((address_space(1))) void*)(src), \
    (__attribute__((address_space(3))) void*)(dst), 16, 0, 0)

#define STAGE(bf, kt) do { \
    GLL(Ag0 + (kt) * 32, &As[bf][0 * 4096 + w * 512]); \
    GLL(Ag1 + (kt) * 32, &As[bf][1 * 4096 + w * 512]); \
    GLL(Bg0 + (kt) * 32, &Bs[bf][0 * 4096 + w * 512]); \
    GLL(Bg1 + (kt) * 32, &Bs[bf][1 * 4096 + w * 512]); \
  } while (0)

  f32x4 acc[8][4] = {};
  const int rchunk = ((l >> 4) ^ (((l & 15) >> 1) & 3)) * 8;  // static read chunk (elems)

  STAGE(0, 0);
  int buf = 0;
  for (int t = 0; t < 64; ++t) {
    __builtin_amdgcn_s_barrier();              // all waves done reading buf^1 (tile t-1)
    __builtin_amdgcn_sched_barrier(0);
    if (t < 63) {
      STAGE(buf ^ 1, t + 1);
      __builtin_amdgcn_sched_barrier(0);
      asm volatile("s_waitcnt vmcnt(4)" ::: "memory");   // own tile-t loads done
    } else {
      asm volatile("s_waitcnt vmcnt(0)" ::: "memory");
    }
    __builtin_amdgcn_sched_barrier(0);
    __builtin_amdgcn_s_barrier();              // everyone's tile-t loads done
    __builtin_amdgcn_sched_barrier(0);

    {
      const unsigned short* Asb = &As[buf][0];
      const unsigned short* Bsb = &Bs[buf][0];
      short8 bfr[4];
#pragma unroll
      for (int n = 0; n < 4; ++n) {
        const int row = wc * 64 + n * 16 + (l & 15);
        bfr[n] = *(const short8*)&Bsb[row * 32 + rchunk];
      }
      __builtin_amdgcn_s_setprio(1);
#pragma unroll
      for (int m = 0; m < 8; ++m) {
        const int row = wr * 128 + m * 16 + (l & 15);
        short8 af = *(const short8*)&Asb[row * 32 + rchunk];
#pragma unroll
        for (int n = 0; n < 4; ++n)
          acc[m][n] = __builtin_amdgcn_mfma_f32_16x16x32_bf16(af, bfr[n], acc[m][n], 0, 0, 0);
      }
      __builtin_amdgcn_s_setprio(0);
    }
    buf ^= 1;
  }
#undef STAGE
#undef GLL

  // epilogue: output chunk + bias selected by tn>>3 (block-uniform; 2048/256=8)
  const int bsel = tn >> 3;
  const float* bp = (bsel == 0) ? b0 : ((bsel == 1) ? b1 : b2);
  OUT_T* Cb = C + (size_t)bsel * ((size_t)8192 * DMODEL);
  const int row0 = tm * 256 + wr * 128 + ((l >> 4) * 4);
  const int lc0 = (tn & 7) * 256 + wc * 64 + (l & 15);
#pragma unroll
  for (int n = 0; n < 4; ++n) {
    float bv = bp[lc0 + n * 16];
#pragma unroll
    for (int m = 0; m < 8; ++m) {
#pragma unroll
      for (int r = 0; r < 4; ++r) {
        float v = acc[m][n][r] + bv;
        size_t idx = (size_t)(row0 + m * 16 + r) * DMODEL + (lc0 + n * 16);
        if constexpr (sizeof(OUT_T) == 2) ((unsigned short*)Cb)[idx] = f2bf(v);
        else                              ((float*)Cb)[idx] = v;
      }
    }
  }
}

// ---------------- fallback attention (round-0 structure, used if ws too small) ----------------
__global__ __launch_bounds__(256) void attn(const unsigned short* __restrict__ Q,
                                            const unsigned short* __restrict__ K,
                                            const unsigned short* __restrict__ V,
                                            unsigned short* __restrict__ O) {
  __shared__ unsigned short Ks[32 * 136];
  __shared__ unsigned short Vt[128 * 40];
  __shared__ unsigned short Ps[4][16 * 40];

  const int tid = threadIdx.x;
  const int l = tid & 63, w = tid >> 6;
  const int bh = blockIdx.x >> 5, qb = blockIdx.x & 31;
  const int b = bh >> 4, h = bh & 15;
  const size_t base = ((size_t)b * SEQ) * DMODEL + (size_t)h * DHEAD;

  const unsigned short* Qp = Q + base + (size_t)(qb * 64 + w * 16) * DMODEL;
  short8 qf[4];
#pragma unroll
  for (int dc = 0; dc < 4; ++dc)
    qf[dc] = *(const short8*)(Qp + (size_t)(l & 15) * DMODEL + dc * 32 + (l >> 4) * 8);

  f32x4 acc[8] = {};
  float sum[4] = {0.f, 0.f, 0.f, 0.f};

  const int skv = tid >> 3;
  const int sc = (tid & 7) * 16;
  const unsigned short* Kg = K + base + (size_t)skv * DMODEL + sc;
  const unsigned short* Vg = V + base + (size_t)skv * DMODEL + sc;

  const float cexp = 1.4426950408889634f / 128.0f;

  for (int kv0 = 0; kv0 < SEQ; kv0 += 32) {
    __syncthreads();
    short8 ka = *(const short8*)(Kg + (size_t)kv0 * DMODEL);
    short8 kb = *(const short8*)(Kg + (size_t)kv0 * DMODEL + 8);
    *(short8*)&Ks[skv * 136 + sc] = ka;
    *(short8*)&Ks[skv * 136 + sc + 8] = kb;
    short8 va = *(const short8*)(Vg + (size_t)kv0 * DMODEL);
    short8 vb = *(const short8*)(Vg + (size_t)kv0 * DMODEL + 8);
#pragma unroll
    for (int j = 0; j < 8; ++j) {
      Vt[(sc + j) * 40 + skv]     = (unsigned short)va[j];
      Vt[(sc + 8 + j) * 40 + skv] = (unsigned short)vb[j];
    }
    __syncthreads();

    f32x4 s[2];
#pragma unroll
    for (int nh = 0; nh < 2; ++nh) {
      f32x4 t = {};
#pragma unroll
      for (int dc = 0; dc < 4; ++dc) {
        short8 kf = *(const short8*)&Ks[(nh * 16 + (l & 15)) * 136 + dc * 32 + (l >> 4) * 8];
        t = __builtin_amdgcn_mfma_f32_16x16x32_bf16(qf[dc], kf, t, 0, 0, 0);
      }
      s[nh] = t;
    }

#pragma unroll
    for (int nh = 0; nh < 2; ++nh) {
#pragma unroll
      for (int r = 0; r < 4; ++r) {
        float p = exp2f(s[nh][r] * cexp);
        sum[r] += p;
        Ps[w][((l >> 4) * 4 + r) * 40 + (l & 15) + nh * 16] = f2bf(p);
      }
    }

    short8 pf = *(const short8*)&Ps[w][(l & 15) * 40 + (l >> 4) * 8];
#pragma unroll
    for (int db = 0; db < 8; ++db) {
      short8 vf = *(const short8*)&Vt[(db * 16 + (l & 15)) * 40 + (l >> 4) * 8];
      acc[db] = __builtin_amdgcn_mfma_f32_16x16x32_bf16(pf, vf, acc[db], 0, 0, 0);
    }
  }

  float inv[4];
#pragma unroll
  for (int r = 0; r < 4; ++r) {
    float s = sum[r];
    s += __shfl_xor(s, 1);
    s += __shfl_xor(s, 2);
    s += __shfl_xor(s, 4);
    s += __shfl_xor(s, 8);
    inv[r] = 1.0f / s;
  }
  unsigned short* Op = O + base + (size_t)(qb * 64 + w * 16) * DMODEL;
#pragma unroll
  for (int db = 0; db < 8; ++db)
#pragma unroll
    for (int r = 0; r < 4; ++r)
      Op[(size_t)((l >> 4) * 4 + r) * DMODEL + db * 16 + (l & 15)] = f2bf(acc[db][r] * inv[r]);
}

// ---------------- attention v6: 64 q/wave, KVBLK=64, proven 2-deep dbuf skeleton ----------------
__global__ __launch_bounds__(256, 2) void attn6(const unsigned short* __restrict__ Q,
                                                const unsigned short* __restrict__ K,
                                                const unsigned short* __restrict__ VT,
                                                unsigned short* __restrict__ O) {
  __shared__ unsigned short Ks[2][64 * 128];
  __shared__ unsigned short Vs[2][128 * 64];

  const int tid = threadIdx.x;
  const int l = tid & 63, w = tid >> 6;
  const int x32 = l & 31, h = l >> 5;

  const int bid = blockIdx.x;
  const int swz = (bid & 7) * 64 + (bid >> 3);
  const int bh = swz >> 3, qb = swz & 7;
  const int b = bh >> 4, hh = bh & 15;
  const size_t base = ((size_t)b * SEQ) * DMODEL + (size_t)hh * DHEAD;
  const unsigned short* VTb = VT + (size_t)bh * DHEAD * SEQ;

  const unsigned short* Qp = Q + base + (size_t)(qb * 256 + w * 64) * DMODEL;
  short8 qfA[8], qfB[8];
#pragma unroll
  for (int dc = 0; dc < 8; ++dc) {
    qfA[dc] = *(const short8*)(Qp + (size_t)x32 * DMODEL + dc * 16 + h * 8);
    qfB[dc] = *(const short8*)(Qp + (size_t)(x32 + 32) * DMODEL + dc * 16 + h * 8);
  }

  const unsigned short* Kg0 = K + base + (size_t)(w * 16 + (l >> 4)) * DMODEL + (((l & 15) ^ (l >> 4)) * 8);
  const unsigned short* Kg1 = K + base + (size_t)(w * 16 + (l >> 4)) * DMODEL + (((l & 15) ^ ((l >> 4) + 4)) * 8);
  const unsigned short* Vg0 = VTb + (size_t)(w * 32 + (l >> 3)) * SEQ + (((l & 7) ^ (l >> 3)) * 8);

  unsigned short* KsD = &Ks[0][0];
  unsigned short* VsD = &Vs[0][0];

#define GLL(src, dst) __builtin_amdgcn_global_load_lds( \
    (const __attribute__((address_space(1))) void*)(src), \
    (__attribute__((address_space(3))) void*)(dst), 16, 0, 0)

#define STAGE(bf, kv0) do { \
    GLL(Kg0 + (size_t)(kv0) * DMODEL,        KsD + (bf) * 8192 + w * 2048 + 0 * 512); \
    GLL(Kg1 + (size_t)((kv0) + 4) * DMODEL,  KsD + (bf) * 8192 + w * 2048 + 1 * 512); \
    GLL(Kg0 + (size_t)((kv0) + 8) * DMODEL,  KsD + (bf) * 8192 + w * 2048 + 2 * 512); \
    GLL(Kg1 + (size_t)((kv0) + 12) * DMODEL, KsD + (bf) * 8192 + w * 2048 + 3 * 512); \
    GLL(Vg0 + (size_t)0 * SEQ + (kv0),       VsD + (bf) * 8192 + w * 2048 + 0 * 512); \
    GLL(Vg0 + (size_t)8 * SEQ + (kv0),       VsD + (bf) * 8192 + w * 2048 + 1 * 512); \
    GLL(Vg0 + (size_t)16 * SEQ + (kv0),      VsD + (bf) * 8192 + w * 2048 + 2 * 512); \
    GLL(Vg0 + (size_t)24 * SEQ + (kv0),      VsD + (bf) * 8192 + w * 2048 + 3 * 512); \
  } while (0)

  f32x16 acc0[4] = {}, acc1[4] = {};
  float sum0 = 0.f, sum1 = 0.f;
  const float cexp = 1.4426950408889634f / 128.0f;

#define COMPUTE_SUB(bf, s) do { \
    const unsigned short* Kb_ = &Ks[bf][(s) * 32 * 128]; \
    const unsigned short* Vb_ = &Vs[bf][0]; \
    f32x16 sa0 = {}, sa1 = {}; \
    __builtin_amdgcn_s_setprio(1); \
    _Pragma("unroll") \
    for (int dc = 0; dc < 8; ++dc) { \
      short8 kf = *(const short8*)&Kb_[x32 * 128 + (((dc * 2 + h) ^ (x32 & 7)) * 8)]; \
      sa0 = __builtin_amdgcn_mfma_f32_32x32x16_bf16(kf, qfA[dc], sa0, 0, 0, 0); \
      sa1 = __builtin_amdgcn_mfma_f32_32x32x16_bf16(kf, qfB[dc], sa1, 0, 0, 0); \
    } \
    __builtin_amdgcn_s_setprio(0); \
    union { unsigned u[4]; short8 s8; } pf0A, pf1A, pf0B, pf1B; \
    { \
      float p[16]; \
      _Pragma("unroll") \
      for (int r = 0; r < 16; ++r) { p[r] = __builtin_amdgcn_exp2f(sa0[r] * cexp); sum0 += p[r]; } \
      unsigned pk0[4], pk1[4]; \
      _Pragma("unroll") \
      for (int blk = 0; blk < 4; ++blk) { \
        asm("v_cvt_pk_bf16_f32 %0, %1, %2" : "=v"(pk0[blk]) : "v"(p[blk * 4 + 0]), "v"(p[blk * 4 + 1])); \
        asm("v_cvt_pk_bf16_f32 %0, %1, %2" : "=v"(pk1[blk]) : "v"(p[blk * 4 + 2]), "v"(p[blk * 4 + 3])); \
      } \
      unsigned a0 = pk0[0], a1 = pk0[1], b0 = pk1[0], b1 = pk1[1]; \
      asm("v_permlane32_swap_b32 %0, %1" : "+v"(a0), "+v"(a1)); \
      asm("v_permlane32_swap_b32 %0, %1" : "+v"(b0), "+v"(b1)); \
      pf0A.u[0] = a0; pf0A.u[1] = b0; pf0A.u[2] = a1; pf0A.u[3] = b1; \
      unsigned c0 = pk0[2], c1 = pk0[3], d0 = pk1[2], d1 = pk1[3]; \
      asm("v_permlane32_swap_b32 %0, %1" : "+v"(c0), "+v"(c1)); \
      asm("v_permlane32_swap_b32 %0, %1" : "+v"(d0), "+v"(d1)); \
      pf1A.u[0] = c0; pf1A.u[1] = d0; pf1A.u[2] = c1; pf1A.u[3] = d1; \
    } \
    { \
      float p[16]; \
      _Pragma("unroll") \
      for (int r = 0; r < 16; ++r) { p[r] = __builtin_amdgcn_exp2f(sa1[r] * cexp); sum1 += p[r]; } \
      unsigned pk0[4], pk1[4]; \
      _Pragma("unroll") \
      for (int blk = 0; blk < 4; ++blk) { \
        asm("v_cvt_pk_bf16_f32 %0, %1, %2" : "=v"(pk0[blk]) : "v"(p[blk * 4 + 0]), "v"(p[blk * 4 + 1])); \
        asm("v_cvt_pk_bf16_f32 %0, %1, %2" : "=v"(pk1[blk]) : "v"(p[blk * 4 + 2]), "v"(p[blk * 4 + 3])); \
      } \
      unsigned a0 = pk0[0], a1 = pk0[1], b0 = pk1[0], b1 = pk1[1]; \
      asm("v_permlane32_swap_b32 %0, %1" : "+v"(a0), "+v"(a1)); \
      asm("v_permlane32_swap_b32 %0, %1" : "+v"(b0), "+v"(b1)); \
      pf0B.u[0] = a0; pf0B.u[1] = b0; pf0B.u[2] = a1; pf0B.u[3] = b1; \
      unsigned c0 = pk0[2], c1 = pk0[3], d0 = pk1[2], d1 = pk1[3]; \
      asm("v_permlane32_swap_b32 %0, %1" : "+v"(c0), "+v"(c1)); \
      asm("v_permlane32_swap_b32 %0, %1" : "+v"(d0), "+v"(d1)); \
      pf1B.u[0] = c0; pf1B.u[1] = d0; pf1B.u[2] = c1; pf1B.u[3] = d1; \
    } \
    __builtin_amdgcn_s_setprio(1); \
    _Pragma("unroll") \
    for (int db = 0; db < 4; ++db) { \
      const int row = db * 32 + x32; \
      short8 vf0 = *(const short8*)&Vb_[row * 64 + ((((s) * 4 + 0 + h) ^ (row & 7)) * 8)]; \
      short8 vf1 = *(const short8*)&Vb_[row * 64 + ((((s) * 4 + 2 + h) ^ (row & 7)) * 8)]; \
      acc0[db] = __builtin_amdgcn_mfma_f32_32x32x16_bf16(pf0A.s8, vf0, acc0[db], 0, 0, 0); \
      acc1[db] = __builtin_amdgcn_mfma_f32_32x32x16_bf16(pf0B.s8, vf0, acc1[db], 0, 0, 0); \
      acc0[db] = __builtin_amdgcn_mfma_f32_32x32x16_bf16(pf1A.s8, vf1, acc0[db], 0, 0, 0); \
      acc1[db] = __builtin_amdgcn_mfma_f32_32x32x16_bf16(pf1B.s8, vf1, acc1[db], 0, 0, 0); \
    } \
    __builtin_amdgcn_s_setprio(0); \
  } while (0)

  STAGE(0, 0);
  int buf = 0;
  for (int t = 0; t < 32; ++t) {
    __builtin_amdgcn_s_barrier();
    __builtin_amdgcn_sched_barrier(0);
    if (t < 31) {
      STAGE(buf ^ 1, (t + 1) * 64);
      __builtin_amdgcn_sched_barrier(0);
      asm volatile("s_waitcnt vmcnt(8)" ::: "memory");
    } else {
      asm volatile("s_waitcnt vmcnt(0)" ::: "memory");
    }
    __builtin_amdgcn_sched_barrier(0);
    __builtin_amdgcn_s_barrier();
    __builtin_amdgcn_sched_barrier(0);
    COMPUTE_SUB(buf, 0);
    COMPUTE_SUB(buf, 1);
    buf ^= 1;
  }
#undef COMPUTE_SUB
#undef STAGE
#undef GLL

  sum0 += __shfl_xor(sum0, 32);
  sum1 += __shfl_xor(sum1, 32);
  float inv0 = 1.0f / sum0;
  float inv1 = 1.0f / sum1;
  float invq0[16], invq1[16];
#pragma unroll
  for (int r = 0; r < 16; ++r) {
    const int crow = (r & 3) + 8 * (r >> 2) + 4 * h;
    invq0[r] = __shfl(inv0, crow);
    invq1[r] = __shfl(inv1, crow);
  }

  unsigned short* Op = O + base + (size_t)(qb * 256 + w * 64) * DMODEL;
#pragma unroll
  for (int db = 0; db < 4; ++db)
#pragma unroll
    for (int r = 0; r < 16; ++r) {
      const int crow = (r & 3) + 8 * (r >> 2) + 4 * h;
      Op[(size_t)crow * DMODEL + db * 32 + x32] = f2bf(acc0[db][r] * invq0[r]);
      Op[(size_t)(crow + 32) * DMODEL + db * 32 + x32] = f2bf(acc1[db][r] * invq1[r]);
    }
}

// ---------------- launch ----------------
extern "C" void kernel_launch(void* const* d_in, const int* in_sizes, int n_in,
                              void* d_out, int out_size, void* d_ws, size_t ws_size,
                              hipStream_t stream) {
  const float* x  = (const float*)d_in[0];
  const float* Wq = (const float*)d_in[1];
  const float* bq = (const float*)d_in[2];
  const float* Wk = (const float*)d_in[3];
  const float* bk = (const float*)d_in[4];
  const float* Wv = (const float*)d_in[5];
  const float* bv = (const float*)d_in[6];
  const float* Wo = (const float*)d_in[7];
  const float* bo = (const float*)d_in[8];

  char* ws = (char*)d_ws;
  unsigned short* xb  = (unsigned short*)ws;
  unsigned short* WqT = (unsigned short*)(ws + 33554432);   // WqT/WkT/WvT contiguous (8 MiB each)
  unsigned short* WkT = (unsigned short*)(ws + 41943040);
  unsigned short* WvT = (unsigned short*)(ws + 50331648);
  unsigned short* WoT = (unsigned short*)(ws + 58720256);
  unsigned short* Qb  = (unsigned short*)(ws + 67108864);   // Qb/Kb/Vb contiguous (32 MiB each)
  unsigned short* Kb  = (unsigned short*)(ws + 100663296);
  unsigned short* Vb  = (unsigned short*)(ws + 134217728);
  unsigned short* VTg = (unsigned short*)(ws + 167772160);  // 32 MiB, needs ws >= 192 MiB
  unsigned short* Pf  = xb;  // prefinal aliases xb (dead after V projection)

  const bool vt_ok = (ws_size >= (size_t)201326592);

  cvt_f32_bf16<<<16384, 256, 0, stream>>>(x, xb, (BATCH * SEQ * DMODEL) / 4);

  transpose_cvt4<<<dim3(64, 64, 4), dim3(32, 8), 0, stream>>>(Wq, Wk, Wv, Wo, WqT, WkT, WvT, WoT);

  // fused QKV projection: one 8192 x 6144 x 2048 GEMM (weights & outputs contiguous)
  gemm3<unsigned short, 24><<<768, 512, 0, stream>>>(xb, WqT, bq, bk, bv, Qb);

  if (vt_ok) {
    transpose_v<<<16384, dim3(32, 8), 0, stream>>>(Vb, VTg);
    attn6<<<512, 256, 0, stream>>>(Qb, Kb, VTg, Pf);
  } else {
    attn<<<2048, 256, 0, stream>>>(Qb, Kb, Vb, Pf);
  }

  gemm3<float, 8><<<256, 512, 0, stream>>>(Pf, WoT, bo, bo, bo, (float*)d_out);
}

// Round 13
// 549.616 us; speedup vs baseline: 1.0567x; 1.0567x over previous
//
#include <hip/hip_runtime.h>

#define DMODEL 2048
#define SEQ    2048
#define BATCH  4
#define HEADS  16
#define DHEAD  128

typedef __attribute__((ext_vector_type(8))) short short8;
typedef __attribute__((ext_vector_type(4))) float f32x4;
typedef __attribute__((ext_vector_type(16))) float f32x16;

__device__ __forceinline__ unsigned short f2bf(float f) {
  union { float f; unsigned u; } v; v.f = f;
  unsigned r = v.u + 0x7FFFu + ((v.u >> 16) & 1u);
  return (unsigned short)(r >> 16);
}

// ---------------- prep: fp32 -> bf16 (vectorized) ----------------
__global__ __launch_bounds__(256) void cvt_f32_bf16(const float* __restrict__ in,
                                                    unsigned short* __restrict__ out,
                                                    int n4) {
  int i = blockIdx.x * 256 + threadIdx.x;
  if (i >= n4) return;
  float4 v = ((const float4*)in)[i];
  ushort4 o;
  o.x = f2bf(v.x); o.y = f2bf(v.y); o.z = f2bf(v.z); o.w = f2bf(v.w);
  ((ushort4*)out)[i] = o;
}

// ---------------- prep: 4x W[k][n] fp32 -> WT[n][k] bf16, fused ----------------
__global__ __launch_bounds__(256) void transpose_cvt4(const float* __restrict__ w0,
                                                      const float* __restrict__ w1,
                                                      const float* __restrict__ w2,
                                                      const float* __restrict__ w3,
                                                      unsigned short* __restrict__ o0,
                                                      unsigned short* __restrict__ o1,
                                                      unsigned short* __restrict__ o2,
                                                      unsigned short* __restrict__ o3) {
  __shared__ float tile[32][33];
  const int z = blockIdx.z;
  const float* in = (z == 0) ? w0 : (z == 1) ? w1 : (z == 2) ? w2 : w3;
  unsigned short* out = (z == 0) ? o0 : (z == 1) ? o1 : (z == 2) ? o2 : o3;
  const int tx = threadIdx.x, ty = threadIdx.y;
  const int x = blockIdx.x * 32 + tx;
  const int y0 = blockIdx.y * 32;
#pragma unroll
  for (int j = 0; j < 32; j += 8)
    tile[ty + j][tx] = in[(size_t)(y0 + ty + j) * DMODEL + x];
  __syncthreads();
  const int xo = blockIdx.y * 32 + tx;
  const int yo0 = blockIdx.x * 32;
#pragma unroll
  for (int j = 0; j < 32; j += 8)
    out[(size_t)(yo0 + ty + j) * DMODEL + xo] = f2bf(tile[tx][ty + j]);
}

// ---------------- V transpose: Vb[8192][2048] -> VT[64 bh][128 d][2048 l] ----------------
__global__ __launch_bounds__(256) void transpose_v(const unsigned short* __restrict__ in,
                                                   unsigned short* __restrict__ out) {
  __shared__ unsigned short t[32][33];
  const int tx = threadIdx.x, ty = threadIdx.y;
  const int bid = blockIdx.x;
  const int lb = bid & 63;
  const int db = (bid >> 6) & 3;
  const int h  = (bid >> 8) & 15;
  const int b  = bid >> 12;
#pragma unroll
  for (int j = 0; j < 32; j += 8)
    t[ty + j][tx] = in[(size_t)(b * SEQ + lb * 32 + ty + j) * DMODEL + h * DHEAD + db * 32 + tx];
  __syncthreads();
  const size_t ob = ((size_t)(b * HEADS + h) * DHEAD + db * 32) * SEQ + lb * 32;
#pragma unroll
  for (int j = 0; j < 32; j += 8)
    out[ob + (size_t)(ty + j) * SEQ + tx] = t[tx][ty + j];
}

// ---------------- GEMM v6: 256x256 tile, BK=64, 4 waves x 128x128/wave ----------------
// Register-blocked: each B fragment feeds 8 MFMAs, each A fragment 8 -> 32 b128 reads
// per 128 MFMAs/wave/K-tile (1.5x less LDS traffic than 8-wave 128x64 geometry).
// Proven R6/R10 skeleton: BAR; STAGE(16); vmcnt(16); BAR; compute. 2-dbuf, 128 KB LDS.
// Swizzle (proven): 16B-chunk p of row r holds logical chunk p^(r&7); source pre-swizzled.
// Block mapping (R10-proven): NTN=24 -> 2D XCD partition, 4x4 micro-tiles; NTN=8 -> tn-major.
template <typename OUT_T, int NTN>
__global__ __launch_bounds__(256, 1) void gemm6(const unsigned short* __restrict__ A,
                                                const unsigned short* __restrict__ Bt,
                                                const float* __restrict__ b0,
                                                const float* __restrict__ b1,
                                                const float* __restrict__ b2,
                                                OUT_T* __restrict__ C) {
  __shared__ unsigned short As[2][256 * 64];
  __shared__ unsigned short Bs[2][256 * 64];

  const int tid = threadIdx.x;
  const int l = tid & 63, w = tid >> 6;   // 4 waves
  const int wr = w >> 1, wc = w & 1;      // 2x2 of 128x128

  const int bid = blockIdx.x;
  int tm, tn;
  if constexpr (NTN == 24) {
    const int xcd = bid & 7;
    const int idx = bid >> 3;        // 0..95
    const int r = xcd >> 1, c = xcd & 1;
    const int mt = idx >> 4;         // 0..5 micro-tile
    const int i = idx & 15;
    const int mrow = mt & 1, mcol = mt >> 1;   // 2 x 3
    tm = r * 8 + mrow * 4 + (i & 3);
    tn = c * 12 + mcol * 4 + (i >> 2);
  } else {
    const int q8 = (32 * NTN) >> 3;
    const int swz = (bid & 7) * q8 + (bid >> 3);
    tn = swz % NTN;
    tm = swz / NTN;
  }

  // staging: 16 loads/thread/K-tile (8 A + 8 B); instance i covers rows i*32 + (tid>>3)
  const int srow = tid >> 3;                       // 0..31
  const int schunk = (tid & 7) ^ ((tid >> 3) & 7); // pre-swizzled source chunk
  const unsigned short* Ag = A + (size_t)(tm * 256 + srow) * DMODEL + schunk * 8;
  const unsigned short* Bg = Bt + (size_t)(tn * 256 + srow) * DMODEL + schunk * 8;

#define GLL(src, dst) __builtin_amdgcn_global_load_lds( \
    (const __attribute__((address_space(1))) void*)(src), \
    (__attribute__((address_space(3))) void*)(dst), 16, 0, 0)

#define STAGE(bf, kt) do { \
    GLL(Ag + (size_t)(0 * 32) * DMODEL + (kt) * 64, &As[bf][0 * 2048 + w * 512]); \
    GLL(Ag + (size_t)(1 * 32) * DMODEL + (kt) * 64, &As[bf][1 * 2048 + w * 512]); \
    GLL(Ag + (size_t)(2 * 32) * DMODEL + (kt) * 64, &As[bf][2 * 2048 + w * 512]); \
    GLL(Ag + (size_t)(3 * 32) * DMODEL + (kt) * 64, &As[bf][3 * 2048 + w * 512]); \
    GLL(Ag + (size_t)(4 * 32) * DMODEL + (kt) * 64, &As[bf][4 * 2048 + w * 512]); \
    GLL(Ag + (size_t)(5 * 32) * DMODEL + (kt) * 64, &As[bf][5 * 2048 + w * 512]); \
    GLL(Ag + (size_t)(6 * 32) * DMODEL + (kt) * 64, &As[bf][6 * 2048 + w * 512]); \
    GLL(Ag + (size_t)(7 * 32) * DMODEL + (kt) * 64, &As[bf][7 * 2048 + w * 512]); \
    GLL(Bg + (size_t)(0 * 32) * DMODEL + (kt) * 64, &Bs[bf][0 * 2048 + w * 512]); \
    GLL(Bg + (size_t)(1 * 32) * DMODEL + (kt) * 64, &Bs[bf][1 * 2048 + w * 512]); \
    GLL(Bg + (size_t)(2 * 32) * DMODEL + (kt) * 64, &Bs[bf][2 * 2048 + w * 512]); \
    GLL(Bg + (size_t)(3 * 32) * DMODEL + (kt) * 64, &Bs[bf][3 * 2048 + w * 512]); \
    GLL(Bg + (size_t)(4 * 32) * DMODEL + (kt) * 64, &Bs[bf][4 * 2048 + w * 512]); \
    GLL(Bg + (size_t)(5 * 32) * DMODEL + (kt) * 64, &Bs[bf][5 * 2048 + w * 512]); \
    GLL(Bg + (size_t)(6 * 32) * DMODEL + (kt) * 64, &Bs[bf][6 * 2048 + w * 512]); \
    GLL(Bg + (size_t)(7 * 32) * DMODEL + (kt) * 64, &Bs[bf][7 * 2048 + w * 512]); \
  } while (0)

  f32x4 acc[8][8] = {};

  STAGE(0, 0);
  int buf = 0;
  for (int t = 0; t < 32; ++t) {
    __builtin_amdgcn_s_barrier();              // all waves done reading buf^1 (tile t-1)
    __builtin_amdgcn_sched_barrier(0);
    if (t < 31) {
      STAGE(buf ^ 1, t + 1);                   // in-flight: 16 (tile t) + 16 new
      __builtin_amdgcn_sched_barrier(0);
      asm volatile("s_waitcnt vmcnt(16)" ::: "memory");  // tile-t loads complete
    } else {
      asm volatile("s_waitcnt vmcnt(0)" ::: "memory");
    }
    __builtin_amdgcn_sched_barrier(0);
    __builtin_amdgcn_s_barrier();              // everyone's tile-t loads complete
    __builtin_amdgcn_sched_barrier(0);

    {
      const unsigned short* Asb = &As[buf][0];
      const unsigned short* Bsb = &Bs[buf][0];
      // B fragments: 8 n-tiles x 2 k-slices, held across the whole K-tile (64 VGPR)
      short8 bfr[8][2];
#pragma unroll
      for (int n = 0; n < 8; ++n) {
        const int row = wc * 128 + n * 16 + (l & 15);
#pragma unroll
        for (int ks = 0; ks < 2; ++ks)
          bfr[n][ks] = *(const short8*)&Bsb[row * 64 + (((ks * 4 + (l >> 4)) ^ (row & 7)) * 8)];
      }
      __builtin_amdgcn_s_setprio(1);
#pragma unroll
      for (int m = 0; m < 8; ++m) {
        const int row = wr * 128 + m * 16 + (l & 15);
        short8 af0 = *(const short8*)&Asb[row * 64 + (((0 + (l >> 4)) ^ (row & 7)) * 8)];
        short8 af1 = *(const short8*)&Asb[row * 64 + (((4 + (l >> 4)) ^ (row & 7)) * 8)];
#pragma unroll
        for (int n = 0; n < 8; ++n) {
          acc[m][n] = __builtin_amdgcn_mfma_f32_16x16x32_bf16(af0, bfr[n][0], acc[m][n], 0, 0, 0);
          acc[m][n] = __builtin_amdgcn_mfma_f32_16x16x32_bf16(af1, bfr[n][1], acc[m][n], 0, 0, 0);
        }
      }
      __builtin_amdgcn_s_setprio(0);
    }
    buf ^= 1;
  }
#undef STAGE
#undef GLL

  // epilogue: output chunk + bias selected by tn>>3 (block-uniform; 2048/256=8)
  const int bsel = tn >> 3;
  const float* bp = (bsel == 0) ? b0 : ((bsel == 1) ? b1 : b2);
  OUT_T* Cb = C + (size_t)bsel * ((size_t)8192 * DMODEL);
  const int row0 = tm * 256 + wr * 128 + ((l >> 4) * 4);
  const int lc0 = (tn & 7) * 256 + wc * 128 + (l & 15);
#pragma unroll
  for (int n = 0; n < 8; ++n) {
    float bv = bp[lc0 + n * 16];
#pragma unroll
    for (int m = 0; m < 8; ++m) {
#pragma unroll
      for (int r = 0; r < 4; ++r) {
        float v = acc[m][n][r] + bv;
        size_t idx = (size_t)(row0 + m * 16 + r) * DMODEL + (lc0 + n * 16);
        if constexpr (sizeof(OUT_T) == 2) ((unsigned short*)Cb)[idx] = f2bf(v);
        else                              ((float*)Cb)[idx] = v;
      }
    }
  }
}

// ---------------- fallback attention (round-0 structure, used if ws too small) ----------------
__global__ __launch_bounds__(256) void attn(const unsigned short* __restrict__ Q,
                                            const unsigned short* __restrict__ K,
                                            const unsigned short* __restrict__ V,
                                            unsigned short* __restrict__ O) {
  __shared__ unsigned short Ks[32 * 136];
  __shared__ unsigned short Vt[128 * 40];
  __shared__ unsigned short Ps[4][16 * 40];

  const int tid = threadIdx.x;
  const int l = tid & 63, w = tid >> 6;
  const int bh = blockIdx.x >> 5, qb = blockIdx.x & 31;
  const int b = bh >> 4, h = bh & 15;
  const size_t base = ((size_t)b * SEQ) * DMODEL + (size_t)h * DHEAD;

  const unsigned short* Qp = Q + base + (size_t)(qb * 64 + w * 16) * DMODEL;
  short8 qf[4];
#pragma unroll
  for (int dc = 0; dc < 4; ++dc)
    qf[dc] = *(const short8*)(Qp + (size_t)(l & 15) * DMODEL + dc * 32 + (l >> 4) * 8);

  f32x4 acc[8] = {};
  float sum[4] = {0.f, 0.f, 0.f, 0.f};

  const int skv = tid >> 3;
  const int sc = (tid & 7) * 16;
  const unsigned short* Kg = K + base + (size_t)skv * DMODEL + sc;
  const unsigned short* Vg = V + base + (size_t)skv * DMODEL + sc;

  const float cexp = 1.4426950408889634f / 128.0f;

  for (int kv0 = 0; kv0 < SEQ; kv0 += 32) {
    __syncthreads();
    short8 ka = *(const short8*)(Kg + (size_t)kv0 * DMODEL);
    short8 kb = *(const short8*)(Kg + (size_t)kv0 * DMODEL + 8);
    *(short8*)&Ks[skv * 136 + sc] = ka;
    *(short8*)&Ks[skv * 136 + sc + 8] = kb;
    short8 va = *(const short8*)(Vg + (size_t)kv0 * DMODEL);
    short8 vb = *(const short8*)(Vg + (size_t)kv0 * DMODEL + 8);
#pragma unroll
    for (int j = 0; j < 8; ++j) {
      Vt[(sc + j) * 40 + skv]     = (unsigned short)va[j];
      Vt[(sc + 8 + j) * 40 + skv] = (unsigned short)vb[j];
    }
    __syncthreads();

    f32x4 s[2];
#pragma unroll
    for (int nh = 0; nh < 2; ++nh) {
      f32x4 t = {};
#pragma unroll
      for (int dc = 0; dc < 4; ++dc) {
        short8 kf = *(const short8*)&Ks[(nh * 16 + (l & 15)) * 136 + dc * 32 + (l >> 4) * 8];
        t = __builtin_amdgcn_mfma_f32_16x16x32_bf16(qf[dc], kf, t, 0, 0, 0);
      }
      s[nh] = t;
    }

#pragma unroll
    for (int nh = 0; nh < 2; ++nh) {
#pragma unroll
      for (int r = 0; r < 4; ++r) {
        float p = exp2f(s[nh][r] * cexp);
        sum[r] += p;
        Ps[w][((l >> 4) * 4 + r) * 40 + (l & 15) + nh * 16] = f2bf(p);
      }
    }

    short8 pf = *(const short8*)&Ps[w][(l & 15) * 40 + (l >> 4) * 8];
#pragma unroll
    for (int db = 0; db < 8; ++db) {
      short8 vf = *(const short8*)&Vt[(db * 16 + (l & 15)) * 40 + (l >> 4) * 8];
      acc[db] = __builtin_amdgcn_mfma_f32_16x16x32_bf16(pf, vf, acc[db], 0, 0, 0);
    }
  }

  float inv[4];
#pragma unroll
  for (int r = 0; r < 4; ++r) {
    float s = sum[r];
    s += __shfl_xor(s, 1);
    s += __shfl_xor(s, 2);
    s += __shfl_xor(s, 4);
    s += __shfl_xor(s, 8);
    inv[r] = 1.0f / s;
  }
  unsigned short* Op = O + base + (size_t)(qb * 64 + w * 16) * DMODEL;
#pragma unroll
  for (int db = 0; db < 8; ++db)
#pragma unroll
    for (int r = 0; r < 4; ++r)
      Op[(size_t)((l >> 4) * 4 + r) * DMODEL + db * 16 + (l & 15)] = f2bf(acc[db][r] * inv[r]);
}

// ---------------- attention v6: 64 q/wave, KVBLK=64, proven 2-deep dbuf skeleton ----------------
__global__ __launch_bounds__(256, 2) void attn6(const unsigned short* __restrict__ Q,
                                                const unsigned short* __restrict__ K,
                                                const unsigned short* __restrict__ VT,
                                                unsigned short* __restrict__ O) {
  __shared__ unsigned short Ks[2][64 * 128];
  __shared__ unsigned short Vs[2][128 * 64];

  const int tid = threadIdx.x;
  const int l = tid & 63, w = tid >> 6;
  const int x32 = l & 31, h = l >> 5;

  const int bid = blockIdx.x;
  const int swz = (bid & 7) * 64 + (bid >> 3);
  const int bh = swz >> 3, qb = swz & 7;
  const int b = bh >> 4, hh = bh & 15;
  const size_t base = ((size_t)b * SEQ) * DMODEL + (size_t)hh * DHEAD;
  const unsigned short* VTb = VT + (size_t)bh * DHEAD * SEQ;

  const unsigned short* Qp = Q + base + (size_t)(qb * 256 + w * 64) * DMODEL;
  short8 qfA[8], qfB[8];
#pragma unroll
  for (int dc = 0; dc < 8; ++dc) {
    qfA[dc] = *(const short8*)(Qp + (size_t)x32 * DMODEL + dc * 16 + h * 8);
    qfB[dc] = *(const short8*)(Qp + (size_t)(x32 + 32) * DMODEL + dc * 16 + h * 8);
  }

  const unsigned short* Kg0 = K + base + (size_t)(w * 16 + (l >> 4)) * DMODEL + (((l & 15) ^ (l >> 4)) * 8);
  const unsigned short* Kg1 = K + base + (size_t)(w * 16 + (l >> 4)) * DMODEL + (((l & 15) ^ ((l >> 4) + 4)) * 8);
  const unsigned short* Vg0 = VTb + (size_t)(w * 32 + (l >> 3)) * SEQ + (((l & 7) ^ (l >> 3)) * 8);

  unsigned short* KsD = &Ks[0][0];
  unsigned short* VsD = &Vs[0][0];

#define GLL(src, dst) __builtin_amdgcn_global_load_lds( \
    (const __attribute__((address_space(1))) void*)(src), \
    (__attribute__((address_space(3))) void*)(dst), 16, 0, 0)

#define STAGE(bf, kv0) do { \
    GLL(Kg0 + (size_t)(kv0) * DMODEL,        KsD + (bf) * 8192 + w * 2048 + 0 * 512); \
    GLL(Kg1 + (size_t)((kv0) + 4) * DMODEL,  KsD + (bf) * 8192 + w * 2048 + 1 * 512); \
    GLL(Kg0 + (size_t)((kv0) + 8) * DMODEL,  KsD + (bf) * 8192 + w * 2048 + 2 * 512); \
    GLL(Kg1 + (size_t)((kv0) + 12) * DMODEL, KsD + (bf) * 8192 + w * 2048 + 3 * 512); \
    GLL(Vg0 + (size_t)0 * SEQ + (kv0),       VsD + (bf) * 8192 + w * 2048 + 0 * 512); \
    GLL(Vg0 + (size_t)8 * SEQ + (kv0),       VsD + (bf) * 8192 + w * 2048 + 1 * 512); \
    GLL(Vg0 + (size_t)16 * SEQ + (kv0),      VsD + (bf) * 8192 + w * 2048 + 2 * 512); \
    GLL(Vg0 + (size_t)24 * SEQ + (kv0),      VsD + (bf) * 8192 + w * 2048 + 3 * 512); \
  } while (0)

  f32x16 acc0[4] = {}, acc1[4] = {};
  float sum0 = 0.f, sum1 = 0.f;
  const float cexp = 1.4426950408889634f / 128.0f;

#define COMPUTE_SUB(bf, s) do { \
    const unsigned short* Kb_ = &Ks[bf][(s) * 32 * 128]; \
    const unsigned short* Vb_ = &Vs[bf][0]; \
    f32x16 sa0 = {}, sa1 = {}; \
    __builtin_amdgcn_s_setprio(1); \
    _Pragma("unroll") \
    for (int dc = 0; dc < 8; ++dc) { \
      short8 kf = *(const short8*)&Kb_[x32 * 128 + (((dc * 2 + h) ^ (x32 & 7)) * 8)]; \
      sa0 = __builtin_amdgcn_mfma_f32_32x32x16_bf16(kf, qfA[dc], sa0, 0, 0, 0); \
      sa1 = __builtin_amdgcn_mfma_f32_32x32x16_bf16(kf, qfB[dc], sa1, 0, 0, 0); \
    } \
    __builtin_amdgcn_s_setprio(0); \
    union { unsigned u[4]; short8 s8; } pf0A, pf1A, pf0B, pf1B; \
    { \
      float p[16]; \
      _Pragma("unroll") \
      for (int r = 0; r < 16; ++r) { p[r] = __builtin_amdgcn_exp2f(sa0[r] * cexp); sum0 += p[r]; } \
      unsigned pk0[4], pk1[4]; \
      _Pragma("unroll") \
      for (int blk = 0; blk < 4; ++blk) { \
        asm("v_cvt_pk_bf16_f32 %0, %1, %2" : "=v"(pk0[blk]) : "v"(p[blk * 4 + 0]), "v"(p[blk * 4 + 1])); \
        asm("v_cvt_pk_bf16_f32 %0, %1, %2" : "=v"(pk1[blk]) : "v"(p[blk * 4 + 2]), "v"(p[blk * 4 + 3])); \
      } \
      unsigned a0 = pk0[0], a1 = pk0[1], b0 = pk1[0], b1 = pk1[1]; \
      asm("v_permlane32_swap_b32 %0, %1" : "+v"(a0), "+v"(a1)); \
      asm("v_permlane32_swap_b32 %0, %1" : "+v"(b0), "+v"(b1)); \
      pf0A.u[0] = a0; pf0A.u[1] = b0; pf0A.u[2] = a1; pf0A.u[3] = b1; \
      unsigned c0 = pk0[2], c1 = pk0[3], d0 = pk1[2], d1 = pk1[3]; \
      asm("v_permlane32_swap_b32 %0, %1" : "+v"(c0), "+v"(c1)); \
      asm("v_permlane32_swap_b32 %0, %1" : "+v"(d0), "+v"(d1)); \
      pf1A.u[0] = c0; pf1A.u[1] = d0; pf1A.u[2] = c1; pf1A.u[3] = d1; \
    } \
    { \
      float p[16]; \
      _Pragma("unroll") \
      for (int r = 0; r < 16; ++r) { p[r] = __builtin_amdgcn_exp2f(sa1[r] * cexp); sum1 += p[r]; } \
      unsigned pk0[4], pk1[4]; \
      _Pragma("unroll") \
      for (int blk = 0; blk < 4; ++blk) { \
        asm("v_cvt_pk_bf16_f32 %0, %1, %2" : "=v"(pk0[blk]) : "v"(p[blk * 4 + 0]), "v"(p[blk * 4 + 1])); \
        asm("v_cvt_pk_bf16_f32 %0, %1, %2" : "=v"(pk1[blk]) : "v"(p[blk * 4 + 2]), "v"(p[blk * 4 + 3])); \
      } \
      unsigned a0 = pk0[0], a1 = pk0[1], b0 = pk1[0], b1 = pk1[1]; \
      asm("v_permlane32_swap_b32 %0, %1" : "+v"(a0), "+v"(a1)); \
      asm("v_permlane32_swap_b32 %0, %1" : "+v"(b0), "+v"(b1)); \
      pf0B.u[0] = a0; pf0B.u[1] = b0; pf0B.u[2] = a1; pf0B.u[3] = b1; \
      unsigned c0 = pk0[2], c1 = pk0[3], d0 = pk1[2], d1 = pk1[3]; \
      asm("v_permlane32_swap_b32 %0, %1" : "+v"(c0), "+v"(c1)); \
      asm("v_permlane32_swap_b32 %0, %1" : "+v"(d0), "+v"(d1)); \
      pf1B.u[0] = c0; pf1B.u[1] = d0; pf1B.u[2] = c1; pf1B.u[3] = d1; \
    } \
    __builtin_amdgcn_s_setprio(1); \
    _Pragma("unroll") \
    for (int db = 0; db < 4; ++db) { \
      const int row = db * 32 + x32; \
      short8 vf0 = *(const short8*)&Vb_[row * 64 + ((((s) * 4 + 0 + h) ^ (row & 7)) * 8)]; \
      short8 vf1 = *(const short8*)&Vb_[row * 64 + ((((s) * 4 + 2 + h) ^ (row & 7)) * 8)]; \
      acc0[db] = __builtin_amdgcn_mfma_f32_32x32x16_bf16(pf0A.s8, vf0, acc0[db], 0, 0, 0); \
      acc1[db] = __builtin_amdgcn_mfma_f32_32x32x16_bf16(pf0B.s8, vf0, acc1[db], 0, 0, 0); \
      acc0[db] = __builtin_amdgcn_mfma_f32_32x32x16_bf16(pf1A.s8, vf1, acc0[db], 0, 0, 0); \
      acc1[db] = __builtin_amdgcn_mfma_f32_32x32x16_bf16(pf1B.s8, vf1, acc1[db], 0, 0, 0); \
    } \
    __builtin_amdgcn_s_setprio(0); \
  } while (0)

  STAGE(0, 0);
  int buf = 0;
  for (int t = 0; t < 32; ++t) {
    __builtin_amdgcn_s_barrier();
    __builtin_amdgcn_sched_barrier(0);
    if (t < 31) {
      STAGE(buf ^ 1, (t + 1) * 64);
      __builtin_amdgcn_sched_barrier(0);
      asm volatile("s_waitcnt vmcnt(8)" ::: "memory");
    } else {
      asm volatile("s_waitcnt vmcnt(0)" ::: "memory");
    }
    __builtin_amdgcn_sched_barrier(0);
    __builtin_amdgcn_s_barrier();
    __builtin_amdgcn_sched_barrier(0);
    COMPUTE_SUB(buf, 0);
    COMPUTE_SUB(buf, 1);
    buf ^= 1;
  }
#undef COMPUTE_SUB
#undef STAGE
#undef GLL

  sum0 += __shfl_xor(sum0, 32);
  sum1 += __shfl_xor(sum1, 32);
  float inv0 = 1.0f / sum0;
  float inv1 = 1.0f / sum1;
  float invq0[16], invq1[16];
#pragma unroll
  for (int r = 0; r < 16; ++r) {
    const int crow = (r & 3) + 8 * (r >> 2) + 4 * h;
    invq0[r] = __shfl(inv0, crow);
    invq1[r] = __shfl(inv1, crow);
  }

  unsigned short* Op = O + base + (size_t)(qb * 256 + w * 64) * DMODEL;
#pragma unroll
  for (int db = 0; db < 4; ++db)
#pragma unroll
    for (int r = 0; r < 16; ++r) {
      const int crow = (r & 3) + 8 * (r >> 2) + 4 * h;
      Op[(size_t)crow * DMODEL + db * 32 + x32] = f2bf(acc0[db][r] * invq0[r]);
      Op[(size_t)(crow + 32) * DMODEL + db * 32 + x32] = f2bf(acc1[db][r] * invq1[r]);
    }
}

// ---------------- launch ----------------
extern "C" void kernel_launch(void* const* d_in, const int* in_sizes, int n_in,
                              void* d_out, int out_size, void* d_ws, size_t ws_size,
                              hipStream_t stream) {
  const float* x  = (const float*)d_in[0];
  const float* Wq = (const float*)d_in[1];
  const float* bq = (const float*)d_in[2];
  const float* Wk = (const float*)d_in[3];
  const float* bk = (const float*)d_in[4];
  const float* Wv = (const float*)d_in[5];
  const float* bv = (const float*)d_in[6];
  const float* Wo = (const float*)d_in[7];
  const float* bo = (const float*)d_in[8];

  char* ws = (char*)d_ws;
  unsigned short* xb  = (unsigned short*)ws;
  unsigned short* WqT = (unsigned short*)(ws + 33554432);   // WqT/WkT/WvT contiguous (8 MiB each)
  unsigned short* WkT = (unsigned short*)(ws + 41943040);
  unsigned short* WvT = (unsigned short*)(ws + 50331648);
  unsigned short* WoT = (unsigned short*)(ws + 58720256);
  unsigned short* Qb  = (unsigned short*)(ws + 67108864);   // Qb/Kb/Vb contiguous (32 MiB each)
  unsigned short* Kb  = (unsigned short*)(ws + 100663296);
  unsigned short* Vb  = (unsigned short*)(ws + 134217728);
  unsigned short* VTg = (unsigned short*)(ws + 167772160);  // 32 MiB, needs ws >= 192 MiB
  unsigned short* Pf  = xb;  // prefinal aliases xb (dead after V projection)

  const bool vt_ok = (ws_size >= (size_t)201326592);

  cvt_f32_bf16<<<16384, 256, 0, stream>>>(x, xb, (BATCH * SEQ * DMODEL) / 4);

  transpose_cvt4<<<dim3(64, 64, 4), dim3(32, 8), 0, stream>>>(Wq, Wk, Wv, Wo, WqT, WkT, WvT, WoT);

  // fused QKV projection: one 8192 x 6144 x 2048 GEMM (weights & outputs contiguous)
  gemm6<unsigned short, 24><<<768, 256, 0, stream>>>(xb, WqT, bq, bk, bv, Qb);

  if (vt_ok) {
    transpose_v<<<16384, dim3(32, 8), 0, stream>>>(Vb, VTg);
    attn6<<<512, 256, 0, stream>>>(Qb, Kb, VTg, Pf);
  } else {
    attn<<<2048, 256, 0, stream>>>(Qb, Kb, Vb, Pf);
  }

  gemm6<float, 8><<<256, 256, 0, stream>>>(Pf, WoT, bo, bo, bo, (float*)d_out);
}

// Round 14
// 536.962 us; speedup vs baseline: 1.0816x; 1.0236x over previous
//
#include <hip/hip_runtime.h>

#define DMODEL 2048
#define SEQ    2048
#define BATCH  4
#define HEADS  16
#define DHEAD  128

typedef __attribute__((ext_vector_type(8))) short short8;
typedef __attribute__((ext_vector_type(4))) float f32x4;
typedef __attribute__((ext_vector_type(16))) float f32x16;

__device__ __forceinline__ unsigned short f2bf(float f) {
  union { float f; unsigned u; } v; v.f = f;
  unsigned r = v.u + 0x7FFFu + ((v.u >> 16) & 1u);
  return (unsigned short)(r >> 16);
}

// ---------------- prep: fp32 -> bf16 (vectorized) ----------------
__global__ __launch_bounds__(256) void cvt_f32_bf16(const float* __restrict__ in,
                                                    unsigned short* __restrict__ out,
                                                    int n4) {
  int i = blockIdx.x * 256 + threadIdx.x;
  if (i >= n4) return;
  float4 v = ((const float4*)in)[i];
  ushort4 o;
  o.x = f2bf(v.x); o.y = f2bf(v.y); o.z = f2bf(v.z); o.w = f2bf(v.w);
  ((ushort4*)out)[i] = o;
}

// ---------------- prep: 4x W[k][n] fp32 -> WT[n][k] bf16, fused ----------------
__global__ __launch_bounds__(256) void transpose_cvt4(const float* __restrict__ w0,
                                                      const float* __restrict__ w1,
                                                      const float* __restrict__ w2,
                                                      const float* __restrict__ w3,
                                                      unsigned short* __restrict__ o0,
                                                      unsigned short* __restrict__ o1,
                                                      unsigned short* __restrict__ o2,
                                                      unsigned short* __restrict__ o3) {
  __shared__ float tile[32][33];
  const int z = blockIdx.z;
  const float* in = (z == 0) ? w0 : (z == 1) ? w1 : (z == 2) ? w2 : w3;
  unsigned short* out = (z == 0) ? o0 : (z == 1) ? o1 : (z == 2) ? o2 : o3;
  const int tx = threadIdx.x, ty = threadIdx.y;
  const int x = blockIdx.x * 32 + tx;
  const int y0 = blockIdx.y * 32;
#pragma unroll
  for (int j = 0; j < 32; j += 8)
    tile[ty + j][tx] = in[(size_t)(y0 + ty + j) * DMODEL + x];
  __syncthreads();
  const int xo = blockIdx.y * 32 + tx;
  const int yo0 = blockIdx.x * 32;
#pragma unroll
  for (int j = 0; j < 32; j += 8)
    out[(size_t)(yo0 + ty + j) * DMODEL + xo] = f2bf(tile[tx][ty + j]);
}

// ---------------- V transpose: Vb[8192][2048] -> VT[64 bh][128 d][2048 l] ----------------
__global__ __launch_bounds__(256) void transpose_v(const unsigned short* __restrict__ in,
                                                   unsigned short* __restrict__ out) {
  __shared__ unsigned short t[32][33];
  const int tx = threadIdx.x, ty = threadIdx.y;
  const int bid = blockIdx.x;
  const int lb = bid & 63;
  const int db = (bid >> 6) & 3;
  const int h  = (bid >> 8) & 15;
  const int b  = bid >> 12;
#pragma unroll
  for (int j = 0; j < 32; j += 8)
    t[ty + j][tx] = in[(size_t)(b * SEQ + lb * 32 + ty + j) * DMODEL + h * DHEAD + db * 32 + tx];
  __syncthreads();
  const size_t ob = ((size_t)(b * HEADS + h) * DHEAD + db * 32) * SEQ + lb * 32;
#pragma unroll
  for (int j = 0; j < 32; j += 8)
    out[ob + (size_t)(ty + j) * SEQ + tx] = t[tx][ty + j];
}

// ---------------- GEMM v7: R10's gemm2 + wave de-phasing ----------------
// Skeleton (R6/R9/R10-proven): BAR; STAGE_A(4); vmcnt(4); BAR; compute{STAGE_B mid}.
// De-phase: odd waves compute m-half {4..7} first, even waves {0..3} first ->
// cross-wave LDS-read / MFMA overlap without any new sync (wave-uniform branch,
// all static indices). STAGE_B issued at the half boundary for all waves.
// Block mapping (R10-proven): NTN=24 -> 2D XCD partition, 4x4 micro-tiles; NTN=8 -> tn-major.
// LDS [buf][256 r][64 c]; 16B-chunk p of row r holds logical chunk p^(r&7).
template <typename OUT_T, int NTN>
__global__ __launch_bounds__(512, 2) void gemm2(const unsigned short* __restrict__ A,
                                                const unsigned short* __restrict__ Bt,
                                                const float* __restrict__ b0,
                                                const float* __restrict__ b1,
                                                const float* __restrict__ b2,
                                                OUT_T* __restrict__ C) {
  __shared__ unsigned short As[2][256 * 64];
  __shared__ unsigned short Bs[2][256 * 64];

  const int tid = threadIdx.x;
  const int l = tid & 63, w = tid >> 6;
  const int wr = w >> 2, wc = w & 3;

  const int bid = blockIdx.x;
  int tm, tn;
  if constexpr (NTN == 24) {
    const int xcd = bid & 7;
    const int idx = bid >> 3;        // 0..95
    const int r = xcd >> 1, c = xcd & 1;
    const int mt = idx >> 4;         // 0..5 micro-tile
    const int i = idx & 15;
    const int mrow = mt & 1, mcol = mt >> 1;   // 2 x 3
    tm = r * 8 + mrow * 4 + (i & 3);
    tn = c * 12 + mcol * 4 + (i >> 2);
  } else {
    const int q8 = (32 * NTN) >> 3;
    const int swz = (bid & 7) * q8 + (bid >> 3);
    tn = swz % NTN;
    tm = swz / NTN;
  }

  // staging: 8 loads/thread/K-tile; instance i covers rows i*64 + w*8 + (l>>3)
  const int srow = w * 8 + (l >> 3);                 // 0..63
  const int schunk = (l & 7) ^ (l >> 3);             // pre-swizzled source chunk (row&7 == l>>3)
  const unsigned short* Ag = A + (size_t)(tm * 256 + srow) * DMODEL + schunk * 8;
  const unsigned short* Bg = Bt + (size_t)(tn * 256 + srow) * DMODEL + schunk * 8;

#define GLL(src, dst) __builtin_amdgcn_global_load_lds( \
    (const __attribute__((address_space(1))) void*)(src), \
    (__attribute__((address_space(3))) void*)(dst), 16, 0, 0)

#define STAGE_A(bf, kt) do { \
    GLL(Ag + (size_t)0 * 64 * DMODEL + (kt) * 64,   &As[bf][0 * 4096 + w * 512]); \
    GLL(Ag + (size_t)1 * 64 * DMODEL + (kt) * 64,   &As[bf][1 * 4096 + w * 512]); \
    GLL(Ag + (size_t)2 * 64 * DMODEL + (kt) * 64,   &As[bf][2 * 4096 + w * 512]); \
    GLL(Ag + (size_t)3 * 64 * DMODEL + (kt) * 64,   &As[bf][3 * 4096 + w * 512]); \
  } while (0)
#define STAGE_B(bf, kt) do { \
    GLL(Bg + (size_t)0 * 64 * DMODEL + (kt) * 64,   &Bs[bf][0 * 4096 + w * 512]); \
    GLL(Bg + (size_t)1 * 64 * DMODEL + (kt) * 64,   &Bs[bf][1 * 4096 + w * 512]); \
    GLL(Bg + (size_t)2 * 64 * DMODEL + (kt) * 64,   &Bs[bf][2 * 4096 + w * 512]); \
    GLL(Bg + (size_t)3 * 64 * DMODEL + (kt) * 64,   &Bs[bf][3 * 4096 + w * 512]); \
  } while (0)

  f32x4 acc[8][4] = {};

  STAGE_A(0, 0);
  STAGE_B(0, 0);
  int buf = 0;
  for (int t = 0; t < 32; ++t) {
    __builtin_amdgcn_s_barrier();              // all waves done reading buf^1 (tile t-1)
    __builtin_amdgcn_sched_barrier(0);
    if (t < 31) {
      STAGE_A(buf ^ 1, t + 1);                 // in-flight: 8 (tile t) + 4
      __builtin_amdgcn_sched_barrier(0);
      asm volatile("s_waitcnt vmcnt(4)" ::: "memory");   // tile-t loads complete
    } else {
      asm volatile("s_waitcnt vmcnt(0)" ::: "memory");
    }
    __builtin_amdgcn_sched_barrier(0);
    __builtin_amdgcn_s_barrier();              // everyone's tile-t loads complete
    __builtin_amdgcn_sched_barrier(0);

    {
      const unsigned short* Asb = &As[buf][0];
      const unsigned short* Bsb = &Bs[buf][0];
      // B fragments: all 4 n-cols x 2 k-slices (held for the whole K-tile)
      short8 bfr[4][2];
#pragma unroll
      for (int n = 0; n < 4; ++n) {
        const int row = wc * 64 + n * 16 + (l & 15);
#pragma unroll
        for (int ks = 0; ks < 2; ++ks)
          bfr[n][ks] = *(const short8*)&Bsb[row * 64 + (((ks * 4 + (l >> 4)) ^ (row & 7)) * 8)];
      }

      // one m-half: 4 m-tiles starting at mb (compile-time), read af then 8 MFMAs each
#define COMPUTE_HALF(mb) do { \
        __builtin_amdgcn_s_setprio(1); \
        _Pragma("unroll") \
        for (int mi = 0; mi < 4; ++mi) { \
          const int m = (mb) + mi; \
          const int row = wr * 128 + m * 16 + (l & 15); \
          short8 af0 = *(const short8*)&Asb[row * 64 + (((0 + (l >> 4)) ^ (row & 7)) * 8)]; \
          short8 af1 = *(const short8*)&Asb[row * 64 + (((4 + (l >> 4)) ^ (row & 7)) * 8)]; \
          _Pragma("unroll") \
          for (int n = 0; n < 4; ++n) { \
            acc[m][n] = __builtin_amdgcn_mfma_f32_16x16x32_bf16(af0, bfr[n][0], acc[m][n], 0, 0, 0); \
            acc[m][n] = __builtin_amdgcn_mfma_f32_16x16x32_bf16(af1, bfr[n][1], acc[m][n], 0, 0, 0); \
          } \
        } \
        __builtin_amdgcn_s_setprio(0); \
      } while (0)

      // wave de-phasing: odd waves do the high half first (wave-uniform branch)
      if (w & 1) {
        COMPUTE_HALF(4);
        if (t < 31) STAGE_B(buf ^ 1, t + 1);
        COMPUTE_HALF(0);
      } else {
        COMPUTE_HALF(0);
        if (t < 31) STAGE_B(buf ^ 1, t + 1);
        COMPUTE_HALF(4);
      }
#undef COMPUTE_HALF
    }
    buf ^= 1;
  }
#undef STAGE_A
#undef STAGE_B
#undef GLL

  // epilogue: output chunk + bias selected by tn>>3 (block-uniform; 2048/256=8)
  const int bsel = tn >> 3;
  const float* bp = (bsel == 0) ? b0 : ((bsel == 1) ? b1 : b2);
  OUT_T* Cb = C + (size_t)bsel * ((size_t)8192 * DMODEL);
  const int row0 = tm * 256 + wr * 128 + ((l >> 4) * 4);
  const int lc0 = (tn & 7) * 256 + wc * 64 + (l & 15);
#pragma unroll
  for (int n = 0; n < 4; ++n) {
    float bv = bp[lc0 + n * 16];
#pragma unroll
    for (int m = 0; m < 8; ++m) {
#pragma unroll
      for (int r = 0; r < 4; ++r) {
        float v = acc[m][n][r] + bv;
        size_t idx = (size_t)(row0 + m * 16 + r) * DMODEL + (lc0 + n * 16);
        if constexpr (sizeof(OUT_T) == 2) ((unsigned short*)Cb)[idx] = f2bf(v);
        else                              ((float*)Cb)[idx] = v;
      }
    }
  }
}

// ---------------- fallback attention (round-0 structure, used if ws too small) ----------------
__global__ __launch_bounds__(256) void attn(const unsigned short* __restrict__ Q,
                                            const unsigned short* __restrict__ K,
                                            const unsigned short* __restrict__ V,
                                            unsigned short* __restrict__ O) {
  __shared__ unsigned short Ks[32 * 136];
  __shared__ unsigned short Vt[128 * 40];
  __shared__ unsigned short Ps[4][16 * 40];

  const int tid = threadIdx.x;
  const int l = tid & 63, w = tid >> 6;
  const int bh = blockIdx.x >> 5, qb = blockIdx.x & 31;
  const int b = bh >> 4, h = bh & 15;
  const size_t base = ((size_t)b * SEQ) * DMODEL + (size_t)h * DHEAD;

  const unsigned short* Qp = Q + base + (size_t)(qb * 64 + w * 16) * DMODEL;
  short8 qf[4];
#pragma unroll
  for (int dc = 0; dc < 4; ++dc)
    qf[dc] = *(const short8*)(Qp + (size_t)(l & 15) * DMODEL + dc * 32 + (l >> 4) * 8);

  f32x4 acc[8] = {};
  float sum[4] = {0.f, 0.f, 0.f, 0.f};

  const int skv = tid >> 3;
  const int sc = (tid & 7) * 16;
  const unsigned short* Kg = K + base + (size_t)skv * DMODEL + sc;
  const unsigned short* Vg = V + base + (size_t)skv * DMODEL + sc;

  const float cexp = 1.4426950408889634f / 128.0f;

  for (int kv0 = 0; kv0 < SEQ; kv0 += 32) {
    __syncthreads();
    short8 ka = *(const short8*)(Kg + (size_t)kv0 * DMODEL);
    short8 kb = *(const short8*)(Kg + (size_t)kv0 * DMODEL + 8);
    *(short8*)&Ks[skv * 136 + sc] = ka;
    *(short8*)&Ks[skv * 136 + sc + 8] = kb;
    short8 va = *(const short8*)(Vg + (size_t)kv0 * DMODEL);
    short8 vb = *(const short8*)(Vg + (size_t)kv0 * DMODEL + 8);
#pragma unroll
    for (int j = 0; j < 8; ++j) {
      Vt[(sc + j) * 40 + skv]     = (unsigned short)va[j];
      Vt[(sc + 8 + j) * 40 + skv] = (unsigned short)vb[j];
    }
    __syncthreads();

    f32x4 s[2];
#pragma unroll
    for (int nh = 0; nh < 2; ++nh) {
      f32x4 t = {};
#pragma unroll
      for (int dc = 0; dc < 4; ++dc) {
        short8 kf = *(const short8*)&Ks[(nh * 16 + (l & 15)) * 136 + dc * 32 + (l >> 4) * 8];
        t = __builtin_amdgcn_mfma_f32_16x16x32_bf16(qf[dc], kf, t, 0, 0, 0);
      }
      s[nh] = t;
    }

#pragma unroll
    for (int nh = 0; nh < 2; ++nh) {
#pragma unroll
      for (int r = 0; r < 4; ++r) {
        float p = exp2f(s[nh][r] * cexp);
        sum[r] += p;
        Ps[w][((l >> 4) * 4 + r) * 40 + (l & 15) + nh * 16] = f2bf(p);
      }
    }

    short8 pf = *(const short8*)&Ps[w][(l & 15) * 40 + (l >> 4) * 8];
#pragma unroll
    for (int db = 0; db < 8; ++db) {
      short8 vf = *(const short8*)&Vt[(db * 16 + (l & 15)) * 40 + (l >> 4) * 8];
      acc[db] = __builtin_amdgcn_mfma_f32_16x16x32_bf16(pf, vf, acc[db], 0, 0, 0);
    }
  }

  float inv[4];
#pragma unroll
  for (int r = 0; r < 4; ++r) {
    float s = sum[r];
    s += __shfl_xor(s, 1);
    s += __shfl_xor(s, 2);
    s += __shfl_xor(s, 4);
    s += __shfl_xor(s, 8);
    inv[r] = 1.0f / s;
  }
  unsigned short* Op = O + base + (size_t)(qb * 64 + w * 16) * DMODEL;
#pragma unroll
  for (int db = 0; db < 8; ++db)
#pragma unroll
    for (int r = 0; r < 4; ++r)
      Op[(size_t)((l >> 4) * 4 + r) * DMODEL + db * 16 + (l & 15)] = f2bf(acc[db][r] * inv[r]);
}

// ---------------- attention v6: 64 q/wave, KVBLK=64, proven 2-deep dbuf skeleton ----------------
__global__ __launch_bounds__(256, 2) void attn6(const unsigned short* __restrict__ Q,
                                                const unsigned short* __restrict__ K,
                                                const unsigned short* __restrict__ VT,
                                                unsigned short* __restrict__ O) {
  __shared__ unsigned short Ks[2][64 * 128];
  __shared__ unsigned short Vs[2][128 * 64];

  const int tid = threadIdx.x;
  const int l = tid & 63, w = tid >> 6;
  const int x32 = l & 31, h = l >> 5;

  const int bid = blockIdx.x;
  const int swz = (bid & 7) * 64 + (bid >> 3);
  const int bh = swz >> 3, qb = swz & 7;
  const int b = bh >> 4, hh = bh & 15;
  const size_t base = ((size_t)b * SEQ) * DMODEL + (size_t)hh * DHEAD;
  const unsigned short* VTb = VT + (size_t)bh * DHEAD * SEQ;

  const unsigned short* Qp = Q + base + (size_t)(qb * 256 + w * 64) * DMODEL;
  short8 qfA[8], qfB[8];
#pragma unroll
  for (int dc = 0; dc < 8; ++dc) {
    qfA[dc] = *(const short8*)(Qp + (size_t)x32 * DMODEL + dc * 16 + h * 8);
    qfB[dc] = *(const short8*)(Qp + (size_t)(x32 + 32) * DMODEL + dc * 16 + h * 8);
  }

  const unsigned short* Kg0 = K + base + (size_t)(w * 16 + (l >> 4)) * DMODEL + (((l & 15) ^ (l >> 4)) * 8);
  const unsigned short* Kg1 = K + base + (size_t)(w * 16 + (l >> 4)) * DMODEL + (((l & 15) ^ ((l >> 4) + 4)) * 8);
  const unsigned short* Vg0 = VTb + (size_t)(w * 32 + (l >> 3)) * SEQ + (((l & 7) ^ (l >> 3)) * 8);

  unsigned short* KsD = &Ks[0][0];
  unsigned short* VsD = &Vs[0][0];

#define GLL(src, dst) __builtin_amdgcn_global_load_lds( \
    (const __attribute__((address_space(1))) void*)(src), \
    (__attribute__((address_space(3))) void*)(dst), 16, 0, 0)

#define STAGE(bf, kv0) do { \
    GLL(Kg0 + (size_t)(kv0) * DMODEL,        KsD + (bf) * 8192 + w * 2048 + 0 * 512); \
    GLL(Kg1 + (size_t)((kv0) + 4) * DMODEL,  KsD + (bf) * 8192 + w * 2048 + 1 * 512); \
    GLL(Kg0 + (size_t)((kv0) + 8) * DMODEL,  KsD + (bf) * 8192 + w * 2048 + 2 * 512); \
    GLL(Kg1 + (size_t)((kv0) + 12) * DMODEL, KsD + (bf) * 8192 + w * 2048 + 3 * 512); \
    GLL(Vg0 + (size_t)0 * SEQ + (kv0),       VsD + (bf) * 8192 + w * 2048 + 0 * 512); \
    GLL(Vg0 + (size_t)8 * SEQ + (kv0),       VsD + (bf) * 8192 + w * 2048 + 1 * 512); \
    GLL(Vg0 + (size_t)16 * SEQ + (kv0),      VsD + (bf) * 8192 + w * 2048 + 2 * 512); \
    GLL(Vg0 + (size_t)24 * SEQ + (kv0),      VsD + (bf) * 8192 + w * 2048 + 3 * 512); \
  } while (0)

  f32x16 acc0[4] = {}, acc1[4] = {};
  float sum0 = 0.f, sum1 = 0.f;
  const float cexp = 1.4426950408889634f / 128.0f;

#define COMPUTE_SUB(bf, s) do { \
    const unsigned short* Kb_ = &Ks[bf][(s) * 32 * 128]; \
    const unsigned short* Vb_ = &Vs[bf][0]; \
    f32x16 sa0 = {}, sa1 = {}; \
    __builtin_amdgcn_s_setprio(1); \
    _Pragma("unroll") \
    for (int dc = 0; dc < 8; ++dc) { \
      short8 kf = *(const short8*)&Kb_[x32 * 128 + (((dc * 2 + h) ^ (x32 & 7)) * 8)]; \
      sa0 = __builtin_amdgcn_mfma_f32_32x32x16_bf16(kf, qfA[dc], sa0, 0, 0, 0); \
      sa1 = __builtin_amdgcn_mfma_f32_32x32x16_bf16(kf, qfB[dc], sa1, 0, 0, 0); \
    } \
    __builtin_amdgcn_s_setprio(0); \
    union { unsigned u[4]; short8 s8; } pf0A, pf1A, pf0B, pf1B; \
    { \
      float p[16]; \
      _Pragma("unroll") \
      for (int r = 0; r < 16; ++r) { p[r] = __builtin_amdgcn_exp2f(sa0[r] * cexp); sum0 += p[r]; } \
      unsigned pk0[4], pk1[4]; \
      _Pragma("unroll") \
      for (int blk = 0; blk < 4; ++blk) { \
        asm("v_cvt_pk_bf16_f32 %0, %1, %2" : "=v"(pk0[blk]) : "v"(p[blk * 4 + 0]), "v"(p[blk * 4 + 1])); \
        asm("v_cvt_pk_bf16_f32 %0, %1, %2" : "=v"(pk1[blk]) : "v"(p[blk * 4 + 2]), "v"(p[blk * 4 + 3])); \
      } \
      unsigned a0 = pk0[0], a1 = pk0[1], b0 = pk1[0], b1 = pk1[1]; \
      asm("v_permlane32_swap_b32 %0, %1" : "+v"(a0), "+v"(a1)); \
      asm("v_permlane32_swap_b32 %0, %1" : "+v"(b0), "+v"(b1)); \
      pf0A.u[0] = a0; pf0A.u[1] = b0; pf0A.u[2] = a1; pf0A.u[3] = b1; \
      unsigned c0 = pk0[2], c1 = pk0[3], d0 = pk1[2], d1 = pk1[3]; \
      asm("v_permlane32_swap_b32 %0, %1" : "+v"(c0), "+v"(c1)); \
      asm("v_permlane32_swap_b32 %0, %1" : "+v"(d0), "+v"(d1)); \
      pf1A.u[0] = c0; pf1A.u[1] = d0; pf1A.u[2] = c1; pf1A.u[3] = d1; \
    } \
    { \
      float p[16]; \
      _Pragma("unroll") \
      for (int r = 0; r < 16; ++r) { p[r] = __builtin_amdgcn_exp2f(sa1[r] * cexp); sum1 += p[r]; } \
      unsigned pk0[4], pk1[4]; \
      _Pragma("unroll") \
      for (int blk = 0; blk < 4; ++blk) { \
        asm("v_cvt_pk_bf16_f32 %0, %1, %2" : "=v"(pk0[blk]) : "v"(p[blk * 4 + 0]), "v"(p[blk * 4 + 1])); \
        asm("v_cvt_pk_bf16_f32 %0, %1, %2" : "=v"(pk1[blk]) : "v"(p[blk * 4 + 2]), "v"(p[blk * 4 + 3])); \
      } \
      unsigned a0 = pk0[0], a1 = pk0[1], b0 = pk1[0], b1 = pk1[1]; \
      asm("v_permlane32_swap_b32 %0, %1" : "+v"(a0), "+v"(a1)); \
      asm("v_permlane32_swap_b32 %0, %1" : "+v"(b0), "+v"(b1)); \
      pf0B.u[0] = a0; pf0B.u[1] = b0; pf0B.u[2] = a1; pf0B.u[3] = b1; \
      unsigned c0 = pk0[2], c1 = pk0[3], d0 = pk1[2], d1 = pk1[3]; \
      asm("v_permlane32_swap_b32 %0, %1" : "+v"(c0), "+v"(c1)); \
      asm("v_permlane32_swap_b32 %0, %1" : "+v"(d0), "+v"(d1)); \
      pf1B.u[0] = c0; pf1B.u[1] = d0; pf1B.u[2] = c1; pf1B.u[3] = d1; \
    } \
    __builtin_amdgcn_s_setprio(1); \
    _Pragma("unroll") \
    for (int db = 0; db < 4; ++db) { \
      const int row = db * 32 + x32; \
      short8 vf0 = *(const short8*)&Vb_[row * 64 + ((((s) * 4 + 0 + h) ^ (row & 7)) * 8)]; \
      short8 vf1 = *(const short8*)&Vb_[row * 64 + ((((s) * 4 + 2 + h) ^ (row & 7)) * 8)]; \
      acc0[db] = __builtin_amdgcn_mfma_f32_32x32x16_bf16(pf0A.s8, vf0, acc0[db], 0, 0, 0); \
      acc1[db] = __builtin_amdgcn_mfma_f32_32x32x16_bf16(pf0B.s8, vf0, acc1[db], 0, 0, 0); \
      acc0[db] = __builtin_amdgcn_mfma_f32_32x32x16_bf16(pf1A.s8, vf1, acc0[db], 0, 0, 0); \
      acc1[db] = __builtin_amdgcn_mfma_f32_32x32x16_bf16(pf1B.s8, vf1, acc1[db], 0, 0, 0); \
    } \
    __builtin_amdgcn_s_setprio(0); \
  } while (0)

  STAGE(0, 0);
  int buf = 0;
  for (int t = 0; t < 32; ++t) {
    __builtin_amdgcn_s_barrier();
    __builtin_amdgcn_sched_barrier(0);
    if (t < 31) {
      STAGE(buf ^ 1, (t + 1) * 64);
      __builtin_amdgcn_sched_barrier(0);
      asm volatile("s_waitcnt vmcnt(8)" ::: "memory");
    } else {
      asm volatile("s_waitcnt vmcnt(0)" ::: "memory");
    }
    __builtin_amdgcn_sched_barrier(0);
    __builtin_amdgcn_s_barrier();
    __builtin_amdgcn_sched_barrier(0);
    COMPUTE_SUB(buf, 0);
    COMPUTE_SUB(buf, 1);
    buf ^= 1;
  }
#undef COMPUTE_SUB
#undef STAGE
#undef GLL

  sum0 += __shfl_xor(sum0, 32);
  sum1 += __shfl_xor(sum1, 32);
  float inv0 = 1.0f / sum0;
  float inv1 = 1.0f / sum1;
  float invq0[16], invq1[16];
#pragma unroll
  for (int r = 0; r < 16; ++r) {
    const int crow = (r & 3) + 8 * (r >> 2) + 4 * h;
    invq0[r] = __shfl(inv0, crow);
    invq1[r] = __shfl(inv1, crow);
  }

  unsigned short* Op = O + base + (size_t)(qb * 256 + w * 64) * DMODEL;
#pragma unroll
  for (int db = 0; db < 4; ++db)
#pragma unroll
    for (int r = 0; r < 16; ++r) {
      const int crow = (r & 3) + 8 * (r >> 2) + 4 * h;
      Op[(size_t)crow * DMODEL + db * 32 + x32] = f2bf(acc0[db][r] * invq0[r]);
      Op[(size_t)(crow + 32) * DMODEL + db * 32 + x32] = f2bf(acc1[db][r] * invq1[r]);
    }
}

// ---------------- launch ----------------
extern "C" void kernel_launch(void* const* d_in, const int* in_sizes, int n_in,
                              void* d_out, int out_size, void* d_ws, size_t ws_size,
                              hipStream_t stream) {
  const float* x  = (const float*)d_in[0];
  const float* Wq = (const float*)d_in[1];
  const float* bq = (const float*)d_in[2];
  const float* Wk = (const float*)d_in[3];
  const float* bk = (const float*)d_in[4];
  const float* Wv = (const float*)d_in[5];
  const float* bv = (const float*)d_in[6];
  const float* Wo = (const float*)d_in[7];
  const float* bo = (const float*)d_in[8];

  char* ws = (char*)d_ws;
  unsigned short* xb  = (unsigned short*)ws;
  unsigned short* WqT = (unsigned short*)(ws + 33554432);   // WqT/WkT/WvT contiguous (8 MiB each)
  unsigned short* WkT = (unsigned short*)(ws + 41943040);
  unsigned short* WvT = (unsigned short*)(ws + 50331648);
  unsigned short* WoT = (unsigned short*)(ws + 58720256);
  unsigned short* Qb  = (unsigned short*)(ws + 67108864);   // Qb/Kb/Vb contiguous (32 MiB each)
  unsigned short* Kb  = (unsigned short*)(ws + 100663296);
  unsigned short* Vb  = (unsigned short*)(ws + 134217728);
  unsigned short* VTg = (unsigned short*)(ws + 167772160);  // 32 MiB, needs ws >= 192 MiB
  unsigned short* Pf  = xb;  // prefinal aliases xb (dead after V projection)

  const bool vt_ok = (ws_size >= (size_t)201326592);

  cvt_f32_bf16<<<16384, 256, 0, stream>>>(x, xb, (BATCH * SEQ * DMODEL) / 4);

  transpose_cvt4<<<dim3(64, 64, 4), dim3(32, 8), 0, stream>>>(Wq, Wk, Wv, Wo, WqT, WkT, WvT, WoT);

  // fused QKV projection: one 8192 x 6144 x 2048 GEMM (weights & outputs contiguous)
  gemm2<unsigned short, 24><<<768, 512, 0, stream>>>(xb, WqT, bq, bk, bv, Qb);

  if (vt_ok) {
    transpose_v<<<16384, dim3(32, 8), 0, stream>>>(Vb, VTg);
    attn6<<<512, 256, 0, stream>>>(Qb, Kb, VTg, Pf);
  } else {
    attn<<<2048, 256, 0, stream>>>(Qb, Kb, Vb, Pf);
  }

  gemm2<float, 8><<<256, 512, 0, stream>>>(Pf, WoT, bo, bo, bo, (float*)d_out);
}

// Round 15
// 492.804 us; speedup vs baseline: 1.1785x; 1.0896x over previous
//
#include <hip/hip_runtime.h>

#define DMODEL 2048
#define SEQ    2048
#define BATCH  4
#define HEADS  16
#define DHEAD  128

typedef __attribute__((ext_vector_type(8))) short short8;
typedef __attribute__((ext_vector_type(4))) float f32x4;
typedef __attribute__((ext_vector_type(16))) float f32x16;

__device__ __forceinline__ unsigned short f2bf(float f) {
  union { float f; unsigned u; } v; v.f = f;
  unsigned r = v.u + 0x7FFFu + ((v.u >> 16) & 1u);
  return (unsigned short)(r >> 16);
}

// ---------------- prep: fp32 -> bf16 (vectorized) ----------------
__global__ __launch_bounds__(256) void cvt_f32_bf16(const float* __restrict__ in,
                                                    unsigned short* __restrict__ out,
                                                    int n4) {
  int i = blockIdx.x * 256 + threadIdx.x;
  if (i >= n4) return;
  float4 v = ((const float4*)in)[i];
  ushort4 o;
  o.x = f2bf(v.x); o.y = f2bf(v.y); o.z = f2bf(v.z); o.w = f2bf(v.w);
  ((ushort4*)out)[i] = o;
}

// ---------------- prep: 4x W[k][n] fp32 -> WT[n][k] bf16, fused ----------------
__global__ __launch_bounds__(256) void transpose_cvt4(const float* __restrict__ w0,
                                                      const float* __restrict__ w1,
                                                      const float* __restrict__ w2,
                                                      const float* __restrict__ w3,
                                                      unsigned short* __restrict__ o0,
                                                      unsigned short* __restrict__ o1,
                                                      unsigned short* __restrict__ o2,
                                                      unsigned short* __restrict__ o3) {
  __shared__ float tile[32][33];
  const int z = blockIdx.z;
  const float* in = (z == 0) ? w0 : (z == 1) ? w1 : (z == 2) ? w2 : w3;
  unsigned short* out = (z == 0) ? o0 : (z == 1) ? o1 : (z == 2) ? o2 : o3;
  const int tx = threadIdx.x, ty = threadIdx.y;
  const int x = blockIdx.x * 32 + tx;
  const int y0 = blockIdx.y * 32;
#pragma unroll
  for (int j = 0; j < 32; j += 8)
    tile[ty + j][tx] = in[(size_t)(y0 + ty + j) * DMODEL + x];
  __syncthreads();
  const int xo = blockIdx.y * 32 + tx;
  const int yo0 = blockIdx.x * 32;
#pragma unroll
  for (int j = 0; j < 32; j += 8)
    out[(size_t)(yo0 + ty + j) * DMODEL + xo] = f2bf(tile[tx][ty + j]);
}

// ---------------- V transpose: Vb[8192][2048] -> VT[64 bh][128 d][2048 l] ----------------
__global__ __launch_bounds__(256) void transpose_v(const unsigned short* __restrict__ in,
                                                   unsigned short* __restrict__ out) {
  __shared__ unsigned short t[32][33];
  const int tx = threadIdx.x, ty = threadIdx.y;
  const int bid = blockIdx.x;
  const int lb = bid & 63;
  const int db = (bid >> 6) & 3;
  const int h  = (bid >> 8) & 15;
  const int b  = bid >> 12;
#pragma unroll
  for (int j = 0; j < 32; j += 8)
    t[ty + j][tx] = in[(size_t)(b * SEQ + lb * 32 + ty + j) * DMODEL + h * DHEAD + db * 32 + tx];
  __syncthreads();
  const size_t ob = ((size_t)(b * HEADS + h) * DHEAD + db * 32) * SEQ + lb * 32;
#pragma unroll
  for (int j = 0; j < 32; j += 8)
    out[ob + (size_t)(ty + j) * SEQ + tx] = t[tx][ty + j];
}

// ---------------- GEMM v4 (R10 best): 256x256, BK=64, dbuf; quadrant A-prefetch ----------------
// Skeleton (R6-proven): BAR; STAGE_A(4); vmcnt(4); BAR; compute{STAGE_B at p==2}.
// Block mapping: NTN=24 -> 2D XCD partition (4x2), 4x4 micro-tiles (FETCH halved, R10);
// NTN=8 -> tn-major within XCD.
// LDS [buf][256 r][64 c]; 16B-chunk p of row r holds logical chunk p^(r&7).
template <typename OUT_T, int NTN>
__global__ __launch_bounds__(512, 2) void gemm2(const unsigned short* __restrict__ A,
                                                const unsigned short* __restrict__ Bt,
                                                const float* __restrict__ b0,
                                                const float* __restrict__ b1,
                                                const float* __restrict__ b2,
                                                OUT_T* __restrict__ C) {
  __shared__ unsigned short As[2][256 * 64];
  __shared__ unsigned short Bs[2][256 * 64];

  const int tid = threadIdx.x;
  const int l = tid & 63, w = tid >> 6;
  const int wr = w >> 2, wc = w & 3;

  const int bid = blockIdx.x;
  int tm, tn;
  if constexpr (NTN == 24) {
    const int xcd = bid & 7;
    const int idx = bid >> 3;        // 0..95
    const int r = xcd >> 1, c = xcd & 1;
    const int mt = idx >> 4;         // 0..5 micro-tile
    const int i = idx & 15;
    const int mrow = mt & 1, mcol = mt >> 1;   // 2 x 3
    tm = r * 8 + mrow * 4 + (i & 3);
    tn = c * 12 + mcol * 4 + (i >> 2);
  } else {
    const int q8 = (32 * NTN) >> 3;
    const int swz = (bid & 7) * q8 + (bid >> 3);
    tn = swz % NTN;
    tm = swz / NTN;
  }

  // staging: 8 loads/thread/K-tile; instance i covers rows i*64 + w*8 + (l>>3)
  const int srow = w * 8 + (l >> 3);                 // 0..63
  const int schunk = (l & 7) ^ (l >> 3);             // pre-swizzled source chunk (row&7 == l>>3)
  const unsigned short* Ag = A + (size_t)(tm * 256 + srow) * DMODEL + schunk * 8;
  const unsigned short* Bg = Bt + (size_t)(tn * 256 + srow) * DMODEL + schunk * 8;

#define GLL(src, dst) __builtin_amdgcn_global_load_lds( \
    (const __attribute__((address_space(1))) void*)(src), \
    (__attribute__((address_space(3))) void*)(dst), 16, 0, 0)

#define STAGE_A(bf, kt) do { \
    GLL(Ag + (size_t)0 * 64 * DMODEL + (kt) * 64,   &As[bf][0 * 4096 + w * 512]); \
    GLL(Ag + (size_t)1 * 64 * DMODEL + (kt) * 64,   &As[bf][1 * 4096 + w * 512]); \
    GLL(Ag + (size_t)2 * 64 * DMODEL + (kt) * 64,   &As[bf][2 * 4096 + w * 512]); \
    GLL(Ag + (size_t)3 * 64 * DMODEL + (kt) * 64,   &As[bf][3 * 4096 + w * 512]); \
  } while (0)
#define STAGE_B(bf, kt) do { \
    GLL(Bg + (size_t)0 * 64 * DMODEL + (kt) * 64,   &Bs[bf][0 * 4096 + w * 512]); \
    GLL(Bg + (size_t)1 * 64 * DMODEL + (kt) * 64,   &Bs[bf][1 * 4096 + w * 512]); \
    GLL(Bg + (size_t)2 * 64 * DMODEL + (kt) * 64,   &Bs[bf][2 * 4096 + w * 512]); \
    GLL(Bg + (size_t)3 * 64 * DMODEL + (kt) * 64,   &Bs[bf][3 * 4096 + w * 512]); \
  } while (0)

  f32x4 acc[8][4] = {};

  STAGE_A(0, 0);
  STAGE_B(0, 0);
  int buf = 0;
  for (int t = 0; t < 32; ++t) {
    __builtin_amdgcn_s_barrier();              // all waves done reading buf^1 (tile t-1)
    __builtin_amdgcn_sched_barrier(0);
    if (t < 31) {
      STAGE_A(buf ^ 1, t + 1);                 // in-flight: 8 (tile t) + 4
      __builtin_amdgcn_sched_barrier(0);
      asm volatile("s_waitcnt vmcnt(4)" ::: "memory");   // tile-t loads complete
    } else {
      asm volatile("s_waitcnt vmcnt(0)" ::: "memory");
    }
    __builtin_amdgcn_sched_barrier(0);
    __builtin_amdgcn_s_barrier();              // everyone's tile-t loads complete
    __builtin_amdgcn_sched_barrier(0);

    {
      const unsigned short* Asb = &As[buf][0];
      const unsigned short* Bsb = &Bs[buf][0];
      // B fragments: all 4 n-cols x 2 k-slices
      short8 bfr[4][2];
#pragma unroll
      for (int n = 0; n < 4; ++n) {
        const int row = wc * 64 + n * 16 + (l & 15);
#pragma unroll
        for (int ks = 0; ks < 2; ++ks)
          bfr[n][ks] = *(const short8*)&Bsb[row * 64 + (((ks * 4 + (l >> 4)) ^ (row & 7)) * 8)];
      }
      // A quadrant-0 fragments (m = 0,1)
      short8 af[2][2][2];  // [parity][mi][ks]
#pragma unroll
      for (int mi = 0; mi < 2; ++mi) {
        const int row = wr * 128 + mi * 16 + (l & 15);
        af[0][mi][0] = *(const short8*)&Asb[row * 64 + (((0 + (l >> 4)) ^ (row & 7)) * 8)];
        af[0][mi][1] = *(const short8*)&Asb[row * 64 + (((4 + (l >> 4)) ^ (row & 7)) * 8)];
      }
#pragma unroll
      for (int p = 0; p < 4; ++p) {
        const int cur = p & 1, nxt = cur ^ 1;
        // prefetch next quadrant's A fragments (overlaps this quadrant's MFMAs)
        if (p < 3) {
#pragma unroll
          for (int mi = 0; mi < 2; ++mi) {
            const int row = wr * 128 + (p + 1) * 32 + mi * 16 + (l & 15);
            af[nxt][mi][0] = *(const short8*)&Asb[row * 64 + (((0 + (l >> 4)) ^ (row & 7)) * 8)];
            af[nxt][mi][1] = *(const short8*)&Asb[row * 64 + (((4 + (l >> 4)) ^ (row & 7)) * 8)];
          }
        }
        if (p == 2 && t < 31) STAGE_B(buf ^ 1, t + 1);   // second half of tile t+1
        __builtin_amdgcn_s_setprio(1);
#pragma unroll
        for (int mi = 0; mi < 2; ++mi) {
#pragma unroll
          for (int n = 0; n < 4; ++n) {
            acc[p * 2 + mi][n] = __builtin_amdgcn_mfma_f32_16x16x32_bf16(af[cur][mi][0], bfr[n][0], acc[p * 2 + mi][n], 0, 0, 0);
            acc[p * 2 + mi][n] = __builtin_amdgcn_mfma_f32_16x16x32_bf16(af[cur][mi][1], bfr[n][1], acc[p * 2 + mi][n], 0, 0, 0);
          }
        }
        __builtin_amdgcn_s_setprio(0);
      }
    }
    buf ^= 1;
  }
#undef STAGE_A
#undef STAGE_B
#undef GLL

  // epilogue: output chunk + bias selected by tn>>3 (block-uniform; 2048/256=8)
  const int bsel = tn >> 3;
  const float* bp = (bsel == 0) ? b0 : ((bsel == 1) ? b1 : b2);
  OUT_T* Cb = C + (size_t)bsel * ((size_t)8192 * DMODEL);
  const int row0 = tm * 256 + wr * 128 + ((l >> 4) * 4);
  const int lc0 = (tn & 7) * 256 + wc * 64 + (l & 15);
#pragma unroll
  for (int n = 0; n < 4; ++n) {
    float bv = bp[lc0 + n * 16];
#pragma unroll
    for (int m = 0; m < 8; ++m) {
#pragma unroll
      for (int r = 0; r < 4; ++r) {
        float v = acc[m][n][r] + bv;
        size_t idx = (size_t)(row0 + m * 16 + r) * DMODEL + (lc0 + n * 16);
        if constexpr (sizeof(OUT_T) == 2) ((unsigned short*)Cb)[idx] = f2bf(v);
        else                              ((float*)Cb)[idx] = v;
      }
    }
  }
}

// ---------------- fallback attention (round-0 structure, used if ws too small) ----------------
__global__ __launch_bounds__(256) void attn(const unsigned short* __restrict__ Q,
                                            const unsigned short* __restrict__ K,
                                            const unsigned short* __restrict__ V,
                                            unsigned short* __restrict__ O) {
  __shared__ unsigned short Ks[32 * 136];
  __shared__ unsigned short Vt[128 * 40];
  __shared__ unsigned short Ps[4][16 * 40];

  const int tid = threadIdx.x;
  const int l = tid & 63, w = tid >> 6;
  const int bh = blockIdx.x >> 5, qb = blockIdx.x & 31;
  const int b = bh >> 4, h = bh & 15;
  const size_t base = ((size_t)b * SEQ) * DMODEL + (size_t)h * DHEAD;

  const unsigned short* Qp = Q + base + (size_t)(qb * 64 + w * 16) * DMODEL;
  short8 qf[4];
#pragma unroll
  for (int dc = 0; dc < 4; ++dc)
    qf[dc] = *(const short8*)(Qp + (size_t)(l & 15) * DMODEL + dc * 32 + (l >> 4) * 8);

  f32x4 acc[8] = {};
  float sum[4] = {0.f, 0.f, 0.f, 0.f};

  const int skv = tid >> 3;
  const int sc = (tid & 7) * 16;
  const unsigned short* Kg = K + base + (size_t)skv * DMODEL + sc;
  const unsigned short* Vg = V + base + (size_t)skv * DMODEL + sc;

  const float cexp = 1.4426950408889634f / 128.0f;

  for (int kv0 = 0; kv0 < SEQ; kv0 += 32) {
    __syncthreads();
    short8 ka = *(const short8*)(Kg + (size_t)kv0 * DMODEL);
    short8 kb = *(const short8*)(Kg + (size_t)kv0 * DMODEL + 8);
    *(short8*)&Ks[skv * 136 + sc] = ka;
    *(short8*)&Ks[skv * 136 + sc + 8] = kb;
    short8 va = *(const short8*)(Vg + (size_t)kv0 * DMODEL);
    short8 vb = *(const short8*)(Vg + (size_t)kv0 * DMODEL + 8);
#pragma unroll
    for (int j = 0; j < 8; ++j) {
      Vt[(sc + j) * 40 + skv]     = (unsigned short)va[j];
      Vt[(sc + 8 + j) * 40 + skv] = (unsigned short)vb[j];
    }
    __syncthreads();

    f32x4 s[2];
#pragma unroll
    for (int nh = 0; nh < 2; ++nh) {
      f32x4 t = {};
#pragma unroll
      for (int dc = 0; dc < 4; ++dc) {
        short8 kf = *(const short8*)&Ks[(nh * 16 + (l & 15)) * 136 + dc * 32 + (l >> 4) * 8];
        t = __builtin_amdgcn_mfma_f32_16x16x32_bf16(qf[dc], kf, t, 0, 0, 0);
      }
      s[nh] = t;
    }

#pragma unroll
    for (int nh = 0; nh < 2; ++nh) {
#pragma unroll
      for (int r = 0; r < 4; ++r) {
        float p = exp2f(s[nh][r] * cexp);
        sum[r] += p;
        Ps[w][((l >> 4) * 4 + r) * 40 + (l & 15) + nh * 16] = f2bf(p);
      }
    }

    short8 pf = *(const short8*)&Ps[w][(l & 15) * 40 + (l >> 4) * 8];
#pragma unroll
    for (int db = 0; db < 8; ++db) {
      short8 vf = *(const short8*)&Vt[(db * 16 + (l & 15)) * 40 + (l >> 4) * 8];
      acc[db] = __builtin_amdgcn_mfma_f32_16x16x32_bf16(pf, vf, acc[db], 0, 0, 0);
    }
  }

  float inv[4];
#pragma unroll
  for (int r = 0; r < 4; ++r) {
    float s = sum[r];
    s += __shfl_xor(s, 1);
    s += __shfl_xor(s, 2);
    s += __shfl_xor(s, 4);
    s += __shfl_xor(s, 8);
    inv[r] = 1.0f / s;
  }
  unsigned short* Op = O + base + (size_t)(qb * 64 + w * 16) * DMODEL;
#pragma unroll
  for (int db = 0; db < 8; ++db)
#pragma unroll
    for (int r = 0; r < 4; ++r)
      Op[(size_t)((l >> 4) * 4 + r) * DMODEL + db * 16 + (l & 15)] = f2bf(acc[db][r] * inv[r]);
}

// ---------------- attention v6: 64 q/wave, KVBLK=64, proven 2-deep dbuf skeleton ----------------
__global__ __launch_bounds__(256, 2) void attn6(const unsigned short* __restrict__ Q,
                                                const unsigned short* __restrict__ K,
                                                const unsigned short* __restrict__ VT,
                                                unsigned short* __restrict__ O) {
  __shared__ unsigned short Ks[2][64 * 128];
  __shared__ unsigned short Vs[2][128 * 64];

  const int tid = threadIdx.x;
  const int l = tid & 63, w = tid >> 6;
  const int x32 = l & 31, h = l >> 5;

  const int bid = blockIdx.x;
  const int swz = (bid & 7) * 64 + (bid >> 3);
  const int bh = swz >> 3, qb = swz & 7;
  const int b = bh >> 4, hh = bh & 15;
  const size_t base = ((size_t)b * SEQ) * DMODEL + (size_t)hh * DHEAD;
  const unsigned short* VTb = VT + (size_t)bh * DHEAD * SEQ;

  const unsigned short* Qp = Q + base + (size_t)(qb * 256 + w * 64) * DMODEL;
  short8 qfA[8], qfB[8];
#pragma unroll
  for (int dc = 0; dc < 8; ++dc) {
    qfA[dc] = *(const short8*)(Qp + (size_t)x32 * DMODEL + dc * 16 + h * 8);
    qfB[dc] = *(const short8*)(Qp + (size_t)(x32 + 32) * DMODEL + dc * 16 + h * 8);
  }

  const unsigned short* Kg0 = K + base + (size_t)(w * 16 + (l >> 4)) * DMODEL + (((l & 15) ^ (l >> 4)) * 8);
  const unsigned short* Kg1 = K + base + (size_t)(w * 16 + (l >> 4)) * DMODEL + (((l & 15) ^ ((l >> 4) + 4)) * 8);
  const unsigned short* Vg0 = VTb + (size_t)(w * 32 + (l >> 3)) * SEQ + (((l & 7) ^ (l >> 3)) * 8);

  unsigned short* KsD = &Ks[0][0];
  unsigned short* VsD = &Vs[0][0];

#define GLL(src, dst) __builtin_amdgcn_global_load_lds( \
    (const __attribute__((address_space(1))) void*)(src), \
    (__attribute__((address_space(3))) void*)(dst), 16, 0, 0)

#define STAGE(bf, kv0) do { \
    GLL(Kg0 + (size_t)(kv0) * DMODEL,        KsD + (bf) * 8192 + w * 2048 + 0 * 512); \
    GLL(Kg1 + (size_t)((kv0) + 4) * DMODEL,  KsD + (bf) * 8192 + w * 2048 + 1 * 512); \
    GLL(Kg0 + (size_t)((kv0) + 8) * DMODEL,  KsD + (bf) * 8192 + w * 2048 + 2 * 512); \
    GLL(Kg1 + (size_t)((kv0) + 12) * DMODEL, KsD + (bf) * 8192 + w * 2048 + 3 * 512); \
    GLL(Vg0 + (size_t)0 * SEQ + (kv0),       VsD + (bf) * 8192 + w * 2048 + 0 * 512); \
    GLL(Vg0 + (size_t)8 * SEQ + (kv0),       VsD + (bf) * 8192 + w * 2048 + 1 * 512); \
    GLL(Vg0 + (size_t)16 * SEQ + (kv0),      VsD + (bf) * 8192 + w * 2048 + 2 * 512); \
    GLL(Vg0 + (size_t)24 * SEQ + (kv0),      VsD + (bf) * 8192 + w * 2048 + 3 * 512); \
  } while (0)

  f32x16 acc0[4] = {}, acc1[4] = {};
  float sum0 = 0.f, sum1 = 0.f;
  const float cexp = 1.4426950408889634f / 128.0f;

#define COMPUTE_SUB(bf, s) do { \
    const unsigned short* Kb_ = &Ks[bf][(s) * 32 * 128]; \
    const unsigned short* Vb_ = &Vs[bf][0]; \
    f32x16 sa0 = {}, sa1 = {}; \
    __builtin_amdgcn_s_setprio(1); \
    _Pragma("unroll") \
    for (int dc = 0; dc < 8; ++dc) { \
      short8 kf = *(const short8*)&Kb_[x32 * 128 + (((dc * 2 + h) ^ (x32 & 7)) * 8)]; \
      sa0 = __builtin_amdgcn_mfma_f32_32x32x16_bf16(kf, qfA[dc], sa0, 0, 0, 0); \
      sa1 = __builtin_amdgcn_mfma_f32_32x32x16_bf16(kf, qfB[dc], sa1, 0, 0, 0); \
    } \
    __builtin_amdgcn_s_setprio(0); \
    union { unsigned u[4]; short8 s8; } pf0A, pf1A, pf0B, pf1B; \
    { \
      float p[16]; \
      _Pragma("unroll") \
      for (int r = 0; r < 16; ++r) { p[r] = __builtin_amdgcn_exp2f(sa0[r] * cexp); sum0 += p[r]; } \
      unsigned pk0[4], pk1[4]; \
      _Pragma("unroll") \
      for (int blk = 0; blk < 4; ++blk) { \
        asm("v_cvt_pk_bf16_f32 %0, %1, %2" : "=v"(pk0[blk]) : "v"(p[blk * 4 + 0]), "v"(p[blk * 4 + 1])); \
        asm("v_cvt_pk_bf16_f32 %0, %1, %2" : "=v"(pk1[blk]) : "v"(p[blk * 4 + 2]), "v"(p[blk * 4 + 3])); \
      } \
      unsigned a0 = pk0[0], a1 = pk0[1], b0 = pk1[0], b1 = pk1[1]; \
      asm("v_permlane32_swap_b32 %0, %1" : "+v"(a0), "+v"(a1)); \
      asm("v_permlane32_swap_b32 %0, %1" : "+v"(b0), "+v"(b1)); \
      pf0A.u[0] = a0; pf0A.u[1] = b0; pf0A.u[2] = a1; pf0A.u[3] = b1; \
      unsigned c0 = pk0[2], c1 = pk0[3], d0 = pk1[2], d1 = pk1[3]; \
      asm("v_permlane32_swap_b32 %0, %1" : "+v"(c0), "+v"(c1)); \
      asm("v_permlane32_swap_b32 %0, %1" : "+v"(d0), "+v"(d1)); \
      pf1A.u[0] = c0; pf1A.u[1] = d0; pf1A.u[2] = c1; pf1A.u[3] = d1; \
    } \
    { \
      float p[16]; \
      _Pragma("unroll") \
      for (int r = 0; r < 16; ++r) { p[r] = __builtin_amdgcn_exp2f(sa1[r] * cexp); sum1 += p[r]; } \
      unsigned pk0[4], pk1[4]; \
      _Pragma("unroll") \
      for (int blk = 0; blk < 4; ++blk) { \
        asm("v_cvt_pk_bf16_f32 %0, %1, %2" : "=v"(pk0[blk]) : "v"(p[blk * 4 + 0]), "v"(p[blk * 4 + 1])); \
        asm("v_cvt_pk_bf16_f32 %0, %1, %2" : "=v"(pk1[blk]) : "v"(p[blk * 4 + 2]), "v"(p[blk * 4 + 3])); \
      } \
      unsigned a0 = pk0[0], a1 = pk0[1], b0 = pk1[0], b1 = pk1[1]; \
      asm("v_permlane32_swap_b32 %0, %1" : "+v"(a0), "+v"(a1)); \
      asm("v_permlane32_swap_b32 %0, %1" : "+v"(b0), "+v"(b1)); \
      pf0B.u[0] = a0; pf0B.u[1] = b0; pf0B.u[2] = a1; pf0B.u[3] = b1; \
      unsigned c0 = pk0[2], c1 = pk0[3], d0 = pk1[2], d1 = pk1[3]; \
      asm("v_permlane32_swap_b32 %0, %1" : "+v"(c0), "+v"(c1)); \
      asm("v_permlane32_swap_b32 %0, %1" : "+v"(d0), "+v"(d1)); \
      pf1B.u[0] = c0; pf1B.u[1] = d0; pf1B.u[2] = c1; pf1B.u[3] = d1; \
    } \
    __builtin_amdgcn_s_setprio(1); \
    _Pragma("unroll") \
    for (int db = 0; db < 4; ++db) { \
      const int row = db * 32 + x32; \
      short8 vf0 = *(const short8*)&Vb_[row * 64 + ((((s) * 4 + 0 + h) ^ (row & 7)) * 8)]; \
      short8 vf1 = *(const short8*)&Vb_[row * 64 + ((((s) * 4 + 2 + h) ^ (row & 7)) * 8)]; \
      acc0[db] = __builtin_amdgcn_mfma_f32_32x32x16_bf16(pf0A.s8, vf0, acc0[db], 0, 0, 0); \
      acc1[db] = __builtin_amdgcn_mfma_f32_32x32x16_bf16(pf0B.s8, vf0, acc1[db], 0, 0, 0); \
      acc0[db] = __builtin_amdgcn_mfma_f32_32x32x16_bf16(pf1A.s8, vf1, acc0[db], 0, 0, 0); \
      acc1[db] = __builtin_amdgcn_mfma_f32_32x32x16_bf16(pf1B.s8, vf1, acc1[db], 0, 0, 0); \
    } \
    __builtin_amdgcn_s_setprio(0); \
  } while (0)

  STAGE(0, 0);
  int buf = 0;
  for (int t = 0; t < 32; ++t) {
    __builtin_amdgcn_s_barrier();
    __builtin_amdgcn_sched_barrier(0);
    if (t < 31) {
      STAGE(buf ^ 1, (t + 1) * 64);
      __builtin_amdgcn_sched_barrier(0);
      asm volatile("s_waitcnt vmcnt(8)" ::: "memory");
    } else {
      asm volatile("s_waitcnt vmcnt(0)" ::: "memory");
    }
    __builtin_amdgcn_sched_barrier(0);
    __builtin_amdgcn_s_barrier();
    __builtin_amdgcn_sched_barrier(0);
    COMPUTE_SUB(buf, 0);
    COMPUTE_SUB(buf, 1);
    buf ^= 1;
  }
#undef COMPUTE_SUB
#undef STAGE
#undef GLL

  sum0 += __shfl_xor(sum0, 32);
  sum1 += __shfl_xor(sum1, 32);
  float inv0 = 1.0f / sum0;
  float inv1 = 1.0f / sum1;
  float invq0[16], invq1[16];
#pragma unroll
  for (int r = 0; r < 16; ++r) {
    const int crow = (r & 3) + 8 * (r >> 2) + 4 * h;
    invq0[r] = __shfl(inv0, crow);
    invq1[r] = __shfl(inv1, crow);
  }

  unsigned short* Op = O + base + (size_t)(qb * 256 + w * 64) * DMODEL;
#pragma unroll
  for (int db = 0; db < 4; ++db)
#pragma unroll
    for (int r = 0; r < 16; ++r) {
      const int crow = (r & 3) + 8 * (r >> 2) + 4 * h;
      Op[(size_t)crow * DMODEL + db * 32 + x32] = f2bf(acc0[db][r] * invq0[r]);
      Op[(size_t)(crow + 32) * DMODEL + db * 32 + x32] = f2bf(acc1[db][r] * invq1[r]);
    }
}

// ---------------- launch ----------------
extern "C" void kernel_launch(void* const* d_in, const int* in_sizes, int n_in,
                              void* d_out, int out_size, void* d_ws, size_t ws_size,
                              hipStream_t stream) {
  const float* x  = (const float*)d_in[0];
  const float* Wq = (const float*)d_in[1];
  const float* bq = (const float*)d_in[2];
  const float* Wk = (const float*)d_in[3];
  const float* bk = (const float*)d_in[4];
  const float* Wv = (const float*)d_in[5];
  const float* bv = (const float*)d_in[6];
  const float* Wo = (const float*)d_in[7];
  const float* bo = (const float*)d_in[8];

  char* ws = (char*)d_ws;
  unsigned short* xb  = (unsigned short*)ws;
  unsigned short* WqT = (unsigned short*)(ws + 33554432);   // WqT/WkT/WvT contiguous (8 MiB each)
  unsigned short* WkT = (unsigned short*)(ws + 41943040);
  unsigned short* WvT = (unsigned short*)(ws + 50331648);
  unsigned short* WoT = (unsigned short*)(ws + 58720256);
  unsigned short* Qb  = (unsigned short*)(ws + 67108864);   // Qb/Kb/Vb contiguous (32 MiB each)
  unsigned short* Kb  = (unsigned short*)(ws + 100663296);
  unsigned short* Vb  = (unsigned short*)(ws + 134217728);
  unsigned short* VTg = (unsigned short*)(ws + 167772160);  // 32 MiB, needs ws >= 192 MiB
  unsigned short* Pf  = xb;  // prefinal aliases xb (dead after V projection)

  const bool vt_ok = (ws_size >= (size_t)201326592);

  cvt_f32_bf16<<<16384, 256, 0, stream>>>(x, xb, (BATCH * SEQ * DMODEL) / 4);

  transpose_cvt4<<<dim3(64, 64, 4), dim3(32, 8), 0, stream>>>(Wq, Wk, Wv, Wo, WqT, WkT, WvT, WoT);

  // fused QKV projection: one 8192 x 6144 x 2048 GEMM (weights & outputs contiguous)
  gemm2<unsigned short, 24><<<768, 512, 0, stream>>>(xb, WqT, bq, bk, bv, Qb);

  if (vt_ok) {
    transpose_v<<<16384, dim3(32, 8), 0, stream>>>(Vb, VTg);
    attn6<<<512, 256, 0, stream>>>(Qb, Kb, VTg, Pf);
  } else {
    attn<<<2048, 256, 0, stream>>>(Qb, Kb, Vb, Pf);
  }

  gemm2<float, 8><<<256, 512, 0, stream>>>(Pf, WoT, bo, bo, bo, (float*)d_out);
}